// Round 2
// baseline (124.843 us; speedup 1.0000x reference)
//
#include <hip/hip_runtime.h>
#include <hip/hip_bf16.h>
#include <math.h>

typedef _Float16 f16x8 __attribute__((ext_vector_type(8)));
typedef _Float16 f16x4 __attribute__((ext_vector_type(4)));
typedef float    f32x4 __attribute__((ext_vector_type(4)));

__device__ __forceinline__ float ldin(const void* p, int i, int f32f) {
  return f32f ? ((const float*)p)[i]
              : __bfloat162float(((const __hip_bfloat16*)p)[i]);
}

__device__ __forceinline__ f32x4 MFMA(f16x8 a, f16x8 b, f32x4 c) {
  return __builtin_amdgcn_mfma_f32_16x16x32_f16(a, b, c, 0, 0, 0);
}

__device__ __forceinline__ float tanh_fast(float x) {
  float e = __expf(2.f * x);
  return 1.f - 2.f * __builtin_amdgcn_rcpf(e + 1.f);
}

__device__ __forceinline__ float redq(float v) {
  v += __shfl_xor(v, 16, 64);
  v += __shfl_xor(v, 32, 64);
  return v;
}

// fragment-linear index: (h,k) -> slot; A/B-frag reads lane-contiguous 16B.
__device__ __forceinline__ int widx(int h, int k) {
  return ((h >> 4) << 10) + ((k >> 5) << 9) + (((k >> 3) & 3) << 7) + ((h & 15) << 3) + (k & 7);
}

// ---- ws layout (f16 units) ----
#define OFF_VW2   0
#define OFF_VW2T  4096
#define OFF_HW2   8192
#define OFF_HW2T  12288
#define OFF_HW3   16384
#define OFF_HW3T  20480
#define OFF_W1V   24576   // packed l1 A-frags: per ht: q0=Whi, q1=Whi, q2=Wlo|0, q3=0
#define OFF_W1H   26624
// f32 constants region (at f16-offset 28672 = byte 57344):
#define CF_BASE   28672
#define C_WGV0 0
#define C_WGV1 64
#define C_WGH0 128
#define C_WGH1 192
#define C_VB1  256
#define C_VB2  320
#define C_HB1  384
#define C_HB2  448
#define C_HB3  512
#define C_W4   576
#define C_K    640
#define C_HB4  656
#define C_FLAG 657
#define C_N    658

// ===========================================================================
// Prep: dtype detection + fragment-linear fp16 panels (+transposes) + packed
// layer-1 A-frags + all f32 constants into ws. Runs once (16 blocks).
// ===========================================================================
__global__ __launch_bounds__(256) void prep_kernel(
    const void* px, const void* pVW1, const void* pVW2,
    const void* pHW1, const void* pHW2, const void* pHW3,
    const void* pVb1, const void* pVb2, const void* pHb1, const void* pHb2,
    const void* pHb3, const void* pHW4, const void* pHb4,
    const void* pG0, const void* pK, _Float16* wsp)
{
  __shared__ int sCnt;
  const int tid = threadIdx.x;
  if (tid == 0) sCnt = 0;
  __syncthreads();
  {
    const unsigned short* xb = (const unsigned short*)px;
    int good = 0;
#pragma unroll
    for (int i = 0; i < 2; ++i) {
      int ex = (xb[tid * 2 + i] >> 7) & 0xFF;
      good += (ex >= 97 && ex <= 157) ? 1 : 0;
    }
    atomicAdd(&sCnt, good);
  }
  __syncthreads();
  const int f32f = (sCnt >= 435) ? 0 : 1;   // >=85% of 512 sane -> bf16 inputs

  const int t = blockIdx.x * 256 + tid;     // 0..4095
  int h = t >> 6, k = t & 63;
  int fw = widx(h, k), tw = widx(k, h);
  _Float16 v;
  v = (_Float16)ldin(pVW2, t, f32f); wsp[OFF_VW2 + fw] = v; wsp[OFF_VW2T + tw] = v;
  v = (_Float16)ldin(pHW2, t, f32f); wsp[OFF_HW2 + fw] = v; wsp[OFF_HW2T + tw] = v;
  v = (_Float16)ldin(pHW3, t, f32f); wsp[OFF_HW3 + fw] = v; wsp[OFF_HW3T + tw] = v;
  if (t < 512) {
    // packed layer-1 A-frags: element (h = t>>3, j = t&7)
    int hh = t >> 3, j = t & 7;
    int base = ((hh >> 4) << 9) + ((hh & 15) << 3) + j;   // ht*512 + mm*8 + j
    float f = ldin(pVW1, t, f32f); _Float16 hi = (_Float16)f;
    _Float16 lo = f32f ? (_Float16)(f - (float)hi) : (_Float16)0.f;
    wsp[OFF_W1V + base]       = hi;
    wsp[OFF_W1V + base + 128] = hi;
    wsp[OFF_W1V + base + 256] = lo;
    wsp[OFF_W1V + base + 384] = (_Float16)0.f;
    f = ldin(pHW1, t, f32f); hi = (_Float16)f;
    lo = f32f ? (_Float16)(f - (float)hi) : (_Float16)0.f;
    wsp[OFF_W1H + base]       = hi;
    wsp[OFF_W1H + base + 128] = hi;
    wsp[OFF_W1H + base + 256] = lo;
    wsp[OFF_W1H + base + 384] = (_Float16)0.f;
  }
  if (blockIdx.x == 0) {
    float* wsF = (float*)(wsp + CF_BASE);
    if (tid < 64) {
      float a0 = 0.f, a1 = 0.f, b0 = 0.f, b1 = 0.f;
#pragma unroll
      for (int nn = 0; nn < 8; ++nn) {
        float g0 = ldin(pG0, 2 * nn, f32f), g1 = ldin(pG0, 2 * nn + 1, f32f);
        float wv = ldin(pVW1, tid * 8 + nn, f32f), wh = ldin(pHW1, tid * 8 + nn, f32f);
        a0 += wv * g0; a1 += wv * g1; b0 += wh * g0; b1 += wh * g1;
      }
      wsF[C_WGV0 + tid] = a0; wsF[C_WGV1 + tid] = a1;
      wsF[C_WGH0 + tid] = b0; wsF[C_WGH1 + tid] = b1;
      wsF[C_VB1 + tid] = ldin(pVb1, tid, f32f);
      wsF[C_VB2 + tid] = ldin(pVb2, tid, f32f);
      wsF[C_HB1 + tid] = ldin(pHb1, tid, f32f);
      wsF[C_HB2 + tid] = ldin(pHb2, tid, f32f);
      wsF[C_HB3 + tid] = ldin(pHb3, tid, f32f);
      wsF[C_W4  + tid] = ldin(pHW4, tid, f32f);
    }
    if (tid < 16) wsF[C_K + tid] = ldin(pK, tid, f32f);
    if (tid == 0) { wsF[C_HB4] = ldin(pHb4, 0, f32f); ((int*)wsF)[C_FLAG] = f32f; }
  }
}

// ===========================================================================
// Main: 512 blocks x 256 thr. Each WAVE owns 16 elements and all 64 h-rows,
// so every GEMM stage is wave-local (DS ops in-order per wave -> no barriers
// between stages; exactly ONE __syncthreads, for the sC copy). Weight A-frags
// stream from ws (global, L2-hot) -> LDS is only 4x2KB act + constants ->
// high occupancy. QP tail: each wave runs the Schur ADMM for its own 16
// elements on lanes<16 with all scalars already in registers (4 concurrent
// tail waves per block, no handoff, no barrier).
// ===========================================================================
__global__ __launch_bounds__(256, 3) void main_kernel(
    const void* px, const _Float16* wsp, float* out)
{
  __shared__ __align__(16) _Float16 sAct[4][1024];
  __shared__ __align__(16) float sC[C_N];

  const int tid = threadIdx.x, lane = tid & 63, w = tid >> 6;
  const int n = lane & 15, q = lane >> 4;
  const int e0 = blockIdx.x * 64 + w * 16;

  const float* cf = (const float*)(wsp + CF_BASE);
  for (int i = tid; i < C_N; i += 256) sC[i] = cf[i];
  const int f32f = ((const int*)cf)[C_FLAG];
  __syncthreads();   // the only block-wide barrier

  // ---- x row (16B/32B vector load), B-frag K-packed + u_nom ----
  float xv[8];
  if (f32f) {
    const f32x4* xp = (const f32x4*)((const float*)px + (e0 + n) * 8);
    f32x4 x0 = xp[0], x1 = xp[1];
#pragma unroll
    for (int j = 0; j < 4; ++j) { xv[j] = x0[j]; xv[4 + j] = x1[j]; }
  } else {
    uint4 u = *(const uint4*)((const unsigned short*)px + (e0 + n) * 8);
    unsigned uu[4] = {u.x, u.y, u.z, u.w};
#pragma unroll
    for (int j = 0; j < 4; ++j) {
      xv[2 * j]     = __uint_as_float(uu[j] << 16);
      xv[2 * j + 1] = __uint_as_float(uu[j] & 0xffff0000u);
    }
  }
  float un0 = 0.f, un1 = 0.f;
  f16x8 xb;
#pragma unroll
  for (int j = 0; j < 8; ++j) {
    _Float16 hh = (_Float16)xv[j];
    float lo = xv[j] - (float)hh;
    xb[j] = (q == 1) ? (_Float16)lo : ((q == 3) ? (_Float16)0.f : hh);
    un0 -= xv[j] * sC[C_K + 2 * j];
    un1 -= xv[j] * sC[C_K + 2 * j + 1];
  }

  _Float16* buf = sAct[w];

  auto gemm64 = [&](int poff, f32x4* acc) {
    f16x8 b0 = *(const f16x8*)(buf + lane * 8);
    f16x8 b1 = *(const f16x8*)(buf + 512 + lane * 8);
#pragma unroll
    for (int ht = 0; ht < 4; ++ht) {
      const _Float16* ap = wsp + poff + ht * 1024 + lane * 8;
      f32x4 c = {0.f, 0.f, 0.f, 0.f};
      c = MFMA(*(const f16x8*)ap, b0, c);
      c = MFMA(*(const f16x8*)(ap + 512), b1, c);
      acc[ht] = c;
    }
  };
  auto l1gemm = [&](int off, f32x4* acc) {
#pragma unroll
    for (int ht = 0; ht < 4; ++ht) {
      const _Float16* ap = wsp + off + ht * 512 + lane * 8;
      f32x4 c = {0.f, 0.f, 0.f, 0.f};
      acc[ht] = MFMA(*(const f16x8*)ap, xb, c);   // Whi*xh + Whi*xl + Wlo*xh
    }
  };
  auto wst = [&](const f32x4* vals) {
#pragma unroll
    for (int ht = 0; ht < 4; ++ht) {
      int aw = ((ht >> 1) << 9) + (((ht & 1) * 2 + (q >> 1)) << 7) + n * 8 + ((q & 1) << 2);
      f16x4 vh;
#pragma unroll
      for (int r = 0; r < 4; ++r) vh[r] = (_Float16)vals[ht][r];
      *(f16x4*)(buf + aw) = vh;
    }
  };

  f32x4 acc[4], tv[4];

  // ===== V net =====
  f32x4 z1V[4], d1V[4];
  l1gemm(OFF_W1V, acc);
#pragma unroll
  for (int ht = 0; ht < 4; ++ht) {
    int hb = ht * 16 + q * 4;
    f32x4 bb = *(const f32x4*)&sC[C_VB1 + hb];
    z1V[ht] = acc[ht];
#pragma unroll
    for (int r = 0; r < 4; ++r) {
      float t = tanh_fast(z1V[ht][r] + bb[r]);
      tv[ht][r] = t; d1V[ht][r] = 1.f - t * t;
    }
  }
  wst(tv);

  gemm64(OFF_VW2, acc);
  float pV = 0.f;
#pragma unroll
  for (int ht = 0; ht < 4; ++ht) {
    int hb = ht * 16 + q * 4;
    f32x4 bb = *(const f32x4*)&sC[C_VB2 + hb];
#pragma unroll
    for (int r = 0; r < 4; ++r) {
      float t = tanh_fast(acc[ht][r] + bb[r]);
      pV += t * t;
      tv[ht][r] = t * (1.f - t * t);          // t2 * d2
    }
  }
  wst(tv);

  gemm64(OFF_VW2T, acc);
  float pgvx = 0.f, plv0 = 0.f, plv1 = 0.f;
#pragma unroll
  for (int ht = 0; ht < 4; ++ht) {
    int hb = ht * 16 + q * 4;
    f32x4 g0 = *(const f32x4*)&sC[C_WGV0 + hb];
    f32x4 g1 = *(const f32x4*)&sC[C_WGV1 + hb];
#pragma unroll
    for (int r = 0; r < 4; ++r) {
      float wt = acc[ht][r] * d1V[ht][r];
      pgvx += wt * z1V[ht][r];
      plv0 += wt * g0[r]; plv1 += wt * g1[r];
    }
  }

  // ===== H net =====
  f32x4 z1H[4], d1H[4], d2H[4];
  l1gemm(OFF_W1H, acc);
#pragma unroll
  for (int ht = 0; ht < 4; ++ht) {
    int hb = ht * 16 + q * 4;
    f32x4 bb = *(const f32x4*)&sC[C_HB1 + hb];
    z1H[ht] = acc[ht];
#pragma unroll
    for (int r = 0; r < 4; ++r) {
      float t = tanh_fast(z1H[ht][r] + bb[r]);
      tv[ht][r] = t; d1H[ht][r] = 1.f - t * t;
    }
  }
  wst(tv);

  gemm64(OFF_HW2, acc);
#pragma unroll
  for (int ht = 0; ht < 4; ++ht) {
    int hb = ht * 16 + q * 4;
    f32x4 bb = *(const f32x4*)&sC[C_HB2 + hb];
#pragma unroll
    for (int r = 0; r < 4; ++r) {
      float t = tanh_fast(acc[ht][r] + bb[r]);
      tv[ht][r] = t; d2H[ht][r] = 1.f - t * t;
    }
  }
  wst(tv);

  gemm64(OFF_HW3, acc);
  float pH = 0.f;
#pragma unroll
  for (int ht = 0; ht < 4; ++ht) {
    int hb = ht * 16 + q * 4;
    f32x4 bb = *(const f32x4*)&sC[C_HB3 + hb];
    f32x4 w4 = *(const f32x4*)&sC[C_W4 + hb];
#pragma unroll
    for (int r = 0; r < 4; ++r) {
      float t = tanh_fast(acc[ht][r] + bb[r]);
      pH += t * w4[r];
      tv[ht][r] = w4[r] * (1.f - t * t);      // v4
    }
  }
  wst(tv);

  gemm64(OFF_HW3T, acc);                      // v3
#pragma unroll
  for (int ht = 0; ht < 4; ++ht)
#pragma unroll
    for (int r = 0; r < 4; ++r) tv[ht][r] = acc[ht][r] * d2H[ht][r];   // bb
  wst(tv);

  gemm64(OFF_HW2T, acc);                      // v2
  float pghx = 0.f, plh0 = 0.f, plh1 = 0.f;
#pragma unroll
  for (int ht = 0; ht < 4; ++ht) {
    int hb = ht * 16 + q * 4;
    f32x4 g0 = *(const f32x4*)&sC[C_WGH0 + hb];
    f32x4 g1 = *(const f32x4*)&sC[C_WGH1 + hb];
#pragma unroll
    for (int r = 0; r < 4; ++r) {
      float wt = acc[ht][r] * d1H[ht][r];
      pghx += wt * z1H[ht][r];
      plh0 += wt * g0[r]; plh1 += wt * g1[r];
    }
  }

  // ---- per-element scalars: reduce over q; lane<16 then owns elem n=lane ----
  float gh0 = redq(plh0), gh1 = redq(plh1), gv0 = redq(plv0), gv1 = redq(plv1);
  float ghx = redq(pghx), gvx = redq(pgvx);
  float V   = 0.5f * redq(pV);
  float H   = redq(pH) + sC[C_HB4];

  // ====== QP tail: per-wave, lanes<16, all state in registers ======
  if (lane >= 16) return;
  const int e = e0 + lane;
  out[98304 + e]  = V;
  out[163840 + e] = H;

  const float im = 1.0f / 1.2f;
  const float sg = 1e-6f;

  float lo0 = ghx - H;
  float hi1 = gvx - V;
  float lo2 = ghx * im - H;
  float hi3 = gvx * im - V;
  float qv0 = -2.f * un0, qv1 = -2.f * un1;

  const float d  = 2.f + sg;
  const float rd = 1.f / d;
  const float al = 1.f + im * im;
  const float be = al * (1.f - rd);
  float S00 = be * (gh0 * gh0 + gv0 * gv0) + d;
  float S11 = be * (gh1 * gh1 + gv1 * gv1) + d;
  float S01 = be * (gh0 * gh1 + gv0 * gv1);
  float idet = 1.f / (S00 * S11 - S01 * S01);
  float i00 = S11 * idet, i11 = S00 * idet, i01 = -S01 * idet;

  float X0 = 0.f, X1 = 0.f, X2 = 0.f, X3 = 0.f, X4 = 0.f, X5 = 0.f;
  float Z[8] = {0.f, 0.f, 0.f, 0.f, 0.f, 0.f, 0.f, 0.f};
  float Y[8] = {0.f, 0.f, 0.f, 0.f, 0.f, 0.f, 0.f, 0.f};

#pragma unroll 1
  for (int it = 0; it < 80; ++it) {
    float t0 = Z[0] - Y[0], t1 = Z[1] - Y[1], t2 = Z[2] - Y[2], t3 = Z[3] - Y[3];
    float t4 = Z[4] - Y[4], t5 = Z[5] - Y[5], t6 = Z[6] - Y[6], t7 = Z[7] - Y[7];
    float tauh = t0 + im * t2, tauv = t1 + im * t3;
    float b0 = sg * X0 - qv0 + gh0 * tauh + gv0 * tauv;
    float b1 = sg * X1 - qv1 + gh1 * tauh + gv1 * tauv;
    float b2 = sg * X2 - 100.f - t1 + t4;
    float b3 = sg * X3 - 100.f - t3 + t5;
    float b4 = sg * X4 - 50.f + t0 + t6;
    float b5 = sg * X5 - 50.f + t2 + t7;
    float pp = b2 + im * b3;
    float s2 = b4 + im * b5;
    float cb0 = gh0 * s2 - gv0 * pp;
    float cb1 = gh1 * s2 - gv1 * pp;
    float u0b = b0 - cb0 * rd;
    float u1b = b1 - cb1 * rd;
    X0 = i00 * u0b + i01 * u1b;
    X1 = i01 * u0b + i11 * u1b;
    float gdH = gh0 * X0 + gh1 * X1;
    float gdV = gv0 * X0 + gv1 * X1;
    X2 = (b2 + gdV) * rd;
    X3 = (b3 + im * gdV) * rd;
    X4 = (b4 - gdH) * rd;
    X5 = (b5 - im * gdH) * rd;
    float zt0 = gdH + X4;
    float zt1 = gdV - X2;
    float zt2 = gdH * im + X5;
    float zt3 = gdV * im - X3;

    float v, zn;
    v = zt0 + Y[0]; zn = fmaxf(v, lo0); Y[0] += zt0 - zn; Z[0] = zn;
    v = zt1 + Y[1]; zn = fminf(v, hi1); Y[1] += zt1 - zn; Z[1] = zn;
    v = zt2 + Y[2]; zn = fmaxf(v, lo2); Y[2] += zt2 - zn; Z[2] = zn;
    v = zt3 + Y[3]; zn = fminf(v, hi3); Y[3] += zt3 - zn; Z[3] = zn;
    v = X2 + Y[4];  zn = fmaxf(v, 0.f); Y[4] += X2 - zn;  Z[4] = zn;
    v = X3 + Y[5];  zn = fmaxf(v, 0.f); Y[5] += X3 - zn;  Z[5] = zn;
    v = X4 + Y[6];  zn = fmaxf(v, 0.f); Y[6] += X4 - zn;  Z[6] = zn;
    v = X5 + Y[7];  zn = fmaxf(v, 0.f); Y[7] += X5 - zn;  Z[7] = zn;
  }

  float relax = 0.5f * (X2 + X3);
  const float cc = 0.5f * (1.f + im);
  float Vdot = cc * (gv0 * X0 + gv1 * X1 - gvx);
  float Hdot = cc * (gh0 * X0 + gh1 * X1 - ghx);

  out[2 * e]      = X0;
  out[2 * e + 1]  = X1;
  out[65536 + e]  = relax;
  out[131072 + e] = Vdot;
  out[196608 + e] = Hdot;
}

extern "C" void kernel_launch(void* const* d_in, const int* in_sizes, int n_in,
                              void* d_out, int out_size, void* d_ws, size_t ws_size,
                              hipStream_t stream) {
  (void)in_sizes; (void)n_in; (void)out_size; (void)ws_size;
  float* out = (float*)d_out;
  _Float16* wsp = (_Float16*)d_ws;
  prep_kernel<<<16, 256, 0, stream>>>(
      d_in[0], d_in[1], d_in[3], d_in[5], d_in[7], d_in[9],
      d_in[2], d_in[4], d_in[6], d_in[8], d_in[10], d_in[11], d_in[12],
      d_in[13], d_in[14], wsp);
  main_kernel<<<512, 256, 0, stream>>>(d_in[0], wsp, out);
}

// Round 3
// 107.610 us; speedup vs baseline: 1.1601x; 1.1601x over previous
//
#include <hip/hip_runtime.h>
#include <hip/hip_bf16.h>
#include <math.h>

typedef _Float16 f16x8 __attribute__((ext_vector_type(8)));
typedef _Float16 f16x4 __attribute__((ext_vector_type(4)));
typedef float    f32x4 __attribute__((ext_vector_type(4)));
typedef float    f32x2 __attribute__((ext_vector_type(2)));

__device__ __forceinline__ float ldin(const void* p, int i, int f32f) {
  return f32f ? ((const float*)p)[i]
              : __bfloat162float(((const __hip_bfloat16*)p)[i]);
}

__device__ __forceinline__ f32x4 MFMA(f16x8 a, f16x8 b, f32x4 c) {
  return __builtin_amdgcn_mfma_f32_16x16x32_f16(a, b, c, 0, 0, 0);
}

__device__ __forceinline__ float tanh_fast(float x) {
  float e = __expf(2.f * x);
  return 1.f - 2.f * __builtin_amdgcn_rcpf(e + 1.f);
}

__device__ __forceinline__ float redq(float v) {
  v += __shfl_xor(v, 16, 64);
  v += __shfl_xor(v, 32, 64);
  return v;
}

// fragment-linear index: (h,k) -> slot; A/B-frag reads lane-contiguous 16B.
__device__ __forceinline__ int widx(int h, int k) {
  return ((h >> 4) << 10) + ((k >> 5) << 9) + (((k >> 3) & 3) << 7) + ((h & 15) << 3) + (k & 7);
}

// ---- ws layout (f16 units) ----
#define OFF_VW2   0
#define OFF_VW2T  4096
#define OFF_HW2   8192
#define OFF_HW2T  12288
#define OFF_HW3   16384
#define OFF_HW3T  20480
#define OFF_W1V   24576   // packed l1 A-frags: per ht: q0=Whi, q1=Whi, q2=Wlo|0, q3=0
#define OFF_W1H   26624
// f32 constants region (at f16-offset 28672 = byte 57344):
#define CF_BASE   28672
#define C_WGV0 0
#define C_WGV1 64
#define C_WGH0 128
#define C_WGH1 192
#define C_VB1  256
#define C_VB2  320
#define C_HB1  384
#define C_HB2  448
#define C_HB3  512
#define C_W4   576
#define C_K    640
#define C_HB4  656
#define C_FLAG 657
#define C_N    658

// ===========================================================================
// Prep: dtype detection + fragment-linear fp16 panels (+transposes) + packed
// layer-1 A-frags + all f32 constants into ws. Runs once (16 blocks).
// ===========================================================================
__global__ __launch_bounds__(256) void prep_kernel(
    const void* px, const void* pVW1, const void* pVW2,
    const void* pHW1, const void* pHW2, const void* pHW3,
    const void* pVb1, const void* pVb2, const void* pHb1, const void* pHb2,
    const void* pHb3, const void* pHW4, const void* pHb4,
    const void* pG0, const void* pK, _Float16* wsp)
{
  __shared__ int sCnt;
  const int tid = threadIdx.x;
  if (tid == 0) sCnt = 0;
  __syncthreads();
  {
    const unsigned short* xb = (const unsigned short*)px;
    int good = 0;
#pragma unroll
    for (int i = 0; i < 2; ++i) {
      int ex = (xb[tid * 2 + i] >> 7) & 0xFF;
      good += (ex >= 97 && ex <= 157) ? 1 : 0;
    }
    atomicAdd(&sCnt, good);
  }
  __syncthreads();
  const int f32f = (sCnt >= 435) ? 0 : 1;   // >=85% of 512 sane -> bf16 inputs

  const int t = blockIdx.x * 256 + tid;     // 0..4095
  int h = t >> 6, k = t & 63;
  int fw = widx(h, k), tw = widx(k, h);
  _Float16 v;
  v = (_Float16)ldin(pVW2, t, f32f); wsp[OFF_VW2 + fw] = v; wsp[OFF_VW2T + tw] = v;
  v = (_Float16)ldin(pHW2, t, f32f); wsp[OFF_HW2 + fw] = v; wsp[OFF_HW2T + tw] = v;
  v = (_Float16)ldin(pHW3, t, f32f); wsp[OFF_HW3 + fw] = v; wsp[OFF_HW3T + tw] = v;
  if (t < 512) {
    // packed layer-1 A-frags: element (h = t>>3, j = t&7)
    int hh = t >> 3, j = t & 7;
    int base = ((hh >> 4) << 9) + ((hh & 15) << 3) + j;   // ht*512 + mm*8 + j
    float f = ldin(pVW1, t, f32f); _Float16 hi = (_Float16)f;
    _Float16 lo = f32f ? (_Float16)(f - (float)hi) : (_Float16)0.f;
    wsp[OFF_W1V + base]       = hi;
    wsp[OFF_W1V + base + 128] = hi;
    wsp[OFF_W1V + base + 256] = lo;
    wsp[OFF_W1V + base + 384] = (_Float16)0.f;
    f = ldin(pHW1, t, f32f); hi = (_Float16)f;
    lo = f32f ? (_Float16)(f - (float)hi) : (_Float16)0.f;
    wsp[OFF_W1H + base]       = hi;
    wsp[OFF_W1H + base + 128] = hi;
    wsp[OFF_W1H + base + 256] = lo;
    wsp[OFF_W1H + base + 384] = (_Float16)0.f;
  }
  if (blockIdx.x == 0) {
    float* wsF = (float*)(wsp + CF_BASE);
    if (tid < 64) {
      float a0 = 0.f, a1 = 0.f, b0 = 0.f, b1 = 0.f;
#pragma unroll
      for (int nn = 0; nn < 8; ++nn) {
        float g0 = ldin(pG0, 2 * nn, f32f), g1 = ldin(pG0, 2 * nn + 1, f32f);
        float wv = ldin(pVW1, tid * 8 + nn, f32f), wh = ldin(pHW1, tid * 8 + nn, f32f);
        a0 += wv * g0; a1 += wv * g1; b0 += wh * g0; b1 += wh * g1;
      }
      wsF[C_WGV0 + tid] = a0; wsF[C_WGV1 + tid] = a1;
      wsF[C_WGH0 + tid] = b0; wsF[C_WGH1 + tid] = b1;
      wsF[C_VB1 + tid] = ldin(pVb1, tid, f32f);
      wsF[C_VB2 + tid] = ldin(pVb2, tid, f32f);
      wsF[C_HB1 + tid] = ldin(pHb1, tid, f32f);
      wsF[C_HB2 + tid] = ldin(pHb2, tid, f32f);
      wsF[C_HB3 + tid] = ldin(pHb3, tid, f32f);
      wsF[C_W4  + tid] = ldin(pHW4, tid, f32f);
    }
    if (tid < 16) wsF[C_K + tid] = ldin(pK, tid, f32f);
    if (tid == 0) { wsF[C_HB4] = ldin(pHb4, 0, f32f); ((int*)wsF)[C_FLAG] = f32f; }
  }
}

// ===========================================================================
// Main: 256 blocks x 512 thr (exactly 1 block/CU). Each WAVE owns 16 elems
// and all 64 h-rows -> every GEMM stage is wave-local (DS in-order per wave,
// no stage barriers). Block owns 128 elems. Two barriers total: sC copy and
// the scalar handoff. QP tail: waves 0 and 2 (SIMD0/SIMD2 by wave%4
// placement) each run the Schur ADMM for 64 elements on 64 FULL lanes;
// all other waves exit -> 4x less tail VALU issue, 1 tail wave per SIMD.
// ===========================================================================
__global__ __launch_bounds__(512, 2) void main_kernel(
    const void* px, const _Float16* wsp, float* out)
{
  __shared__ __align__(16) _Float16 sAct[8][1024];
  __shared__ __align__(16) float sQPs[10][128];
  __shared__ __align__(16) float sC[C_N];

  const int tid = threadIdx.x, lane = tid & 63, w = tid >> 6;
  const int n = lane & 15, q = lane >> 4;
  const int e0 = blockIdx.x * 128 + w * 16;

  const float* cf = (const float*)(wsp + CF_BASE);
  for (int i = tid; i < C_N; i += 512) sC[i] = cf[i];
  const int f32f = ((const int*)cf)[C_FLAG];
  __syncthreads();   // barrier #1: sC ready

  // ---- x row (16B/32B vector load), B-frag K-packed + u_nom ----
  float xv[8];
  if (f32f) {
    const f32x4* xp = (const f32x4*)((const float*)px + (e0 + n) * 8);
    f32x4 x0 = xp[0], x1 = xp[1];
#pragma unroll
    for (int j = 0; j < 4; ++j) { xv[j] = x0[j]; xv[4 + j] = x1[j]; }
  } else {
    uint4 u = *(const uint4*)((const unsigned short*)px + (e0 + n) * 8);
    unsigned uu[4] = {u.x, u.y, u.z, u.w};
#pragma unroll
    for (int j = 0; j < 4; ++j) {
      xv[2 * j]     = __uint_as_float(uu[j] << 16);
      xv[2 * j + 1] = __uint_as_float(uu[j] & 0xffff0000u);
    }
  }
  float un0 = 0.f, un1 = 0.f;
  f16x8 xb;
#pragma unroll
  for (int j = 0; j < 8; ++j) {
    _Float16 hh = (_Float16)xv[j];
    float lo = xv[j] - (float)hh;
    xb[j] = (q == 1) ? (_Float16)lo : ((q == 3) ? (_Float16)0.f : hh);
    un0 -= xv[j] * sC[C_K + 2 * j];
    un1 -= xv[j] * sC[C_K + 2 * j + 1];
  }

  _Float16* buf = sAct[w];

  // A-frags loaded into regs BEFORE B ds_reads so global latency overlaps LDS.
  auto gemm64 = [&](int poff, f32x4* acc) {
    f16x8 a[8];
#pragma unroll
    for (int i = 0; i < 8; ++i)
      a[i] = *(const f16x8*)(wsp + poff + i * 512 + lane * 8);
    f16x8 b0 = *(const f16x8*)(buf + lane * 8);
    f16x8 b1 = *(const f16x8*)(buf + 512 + lane * 8);
#pragma unroll
    for (int ht = 0; ht < 4; ++ht) {
      f32x4 c = {0.f, 0.f, 0.f, 0.f};
      c = MFMA(a[2 * ht], b0, c);
      c = MFMA(a[2 * ht + 1], b1, c);
      acc[ht] = c;
    }
  };
  auto l1gemm = [&](int off, f32x4* acc) {
    f16x8 a[4];
#pragma unroll
    for (int ht = 0; ht < 4; ++ht)
      a[ht] = *(const f16x8*)(wsp + off + ht * 512 + lane * 8);
#pragma unroll
    for (int ht = 0; ht < 4; ++ht) {
      f32x4 c = {0.f, 0.f, 0.f, 0.f};
      acc[ht] = MFMA(a[ht], xb, c);   // Whi*xh + Whi*xl + Wlo*xh
    }
  };
  auto wst = [&](const f32x4* vals) {
#pragma unroll
    for (int ht = 0; ht < 4; ++ht) {
      int aw = ((ht >> 1) << 9) + (((ht & 1) * 2 + (q >> 1)) << 7) + n * 8 + ((q & 1) << 2);
      f16x4 vh;
#pragma unroll
      for (int r = 0; r < 4; ++r) vh[r] = (_Float16)vals[ht][r];
      *(f16x4*)(buf + aw) = vh;
    }
  };

  f32x4 acc[4], tv[4];

  // ===== V net =====
  f32x4 z1V[4], d1V[4];
  l1gemm(OFF_W1V, acc);
#pragma unroll
  for (int ht = 0; ht < 4; ++ht) {
    int hb = ht * 16 + q * 4;
    f32x4 bb = *(const f32x4*)&sC[C_VB1 + hb];
    z1V[ht] = acc[ht];
#pragma unroll
    for (int r = 0; r < 4; ++r) {
      float t = tanh_fast(z1V[ht][r] + bb[r]);
      tv[ht][r] = t; d1V[ht][r] = 1.f - t * t;
    }
  }
  wst(tv);

  gemm64(OFF_VW2, acc);
  float pV = 0.f;
#pragma unroll
  for (int ht = 0; ht < 4; ++ht) {
    int hb = ht * 16 + q * 4;
    f32x4 bb = *(const f32x4*)&sC[C_VB2 + hb];
#pragma unroll
    for (int r = 0; r < 4; ++r) {
      float t = tanh_fast(acc[ht][r] + bb[r]);
      pV += t * t;
      tv[ht][r] = t * (1.f - t * t);          // t2 * d2
    }
  }
  wst(tv);

  gemm64(OFF_VW2T, acc);
  float pgvx = 0.f, plv0 = 0.f, plv1 = 0.f;
#pragma unroll
  for (int ht = 0; ht < 4; ++ht) {
    int hb = ht * 16 + q * 4;
    f32x4 g0 = *(const f32x4*)&sC[C_WGV0 + hb];
    f32x4 g1 = *(const f32x4*)&sC[C_WGV1 + hb];
#pragma unroll
    for (int r = 0; r < 4; ++r) {
      float wt = acc[ht][r] * d1V[ht][r];
      pgvx += wt * z1V[ht][r];
      plv0 += wt * g0[r]; plv1 += wt * g1[r];
    }
  }

  // ===== H net =====
  f32x4 z1H[4], d1H[4], d2H[4];
  l1gemm(OFF_W1H, acc);
#pragma unroll
  for (int ht = 0; ht < 4; ++ht) {
    int hb = ht * 16 + q * 4;
    f32x4 bb = *(const f32x4*)&sC[C_HB1 + hb];
    z1H[ht] = acc[ht];
#pragma unroll
    for (int r = 0; r < 4; ++r) {
      float t = tanh_fast(z1H[ht][r] + bb[r]);
      tv[ht][r] = t; d1H[ht][r] = 1.f - t * t;
    }
  }
  wst(tv);

  gemm64(OFF_HW2, acc);
#pragma unroll
  for (int ht = 0; ht < 4; ++ht) {
    int hb = ht * 16 + q * 4;
    f32x4 bb = *(const f32x4*)&sC[C_HB2 + hb];
#pragma unroll
    for (int r = 0; r < 4; ++r) {
      float t = tanh_fast(acc[ht][r] + bb[r]);
      tv[ht][r] = t; d2H[ht][r] = 1.f - t * t;
    }
  }
  wst(tv);

  gemm64(OFF_HW3, acc);
  float pH = 0.f;
#pragma unroll
  for (int ht = 0; ht < 4; ++ht) {
    int hb = ht * 16 + q * 4;
    f32x4 bb = *(const f32x4*)&sC[C_HB3 + hb];
    f32x4 w4 = *(const f32x4*)&sC[C_W4 + hb];
#pragma unroll
    for (int r = 0; r < 4; ++r) {
      float t = tanh_fast(acc[ht][r] + bb[r]);
      pH += t * w4[r];
      tv[ht][r] = w4[r] * (1.f - t * t);      // v4
    }
  }
  wst(tv);

  gemm64(OFF_HW3T, acc);                      // v3
#pragma unroll
  for (int ht = 0; ht < 4; ++ht)
#pragma unroll
    for (int r = 0; r < 4; ++r) tv[ht][r] = acc[ht][r] * d2H[ht][r];   // bb
  wst(tv);

  gemm64(OFF_HW2T, acc);                      // v2
  float pghx = 0.f, plh0 = 0.f, plh1 = 0.f;
#pragma unroll
  for (int ht = 0; ht < 4; ++ht) {
    int hb = ht * 16 + q * 4;
    f32x4 g0 = *(const f32x4*)&sC[C_WGH0 + hb];
    f32x4 g1 = *(const f32x4*)&sC[C_WGH1 + hb];
#pragma unroll
    for (int r = 0; r < 4; ++r) {
      float wt = acc[ht][r] * d1H[ht][r];
      pghx += wt * z1H[ht][r];
      plh0 += wt * g0[r]; plh1 += wt * g1[r];
    }
  }

  // ---- per-element scalars: reduce over q, hand off via LDS transpose ----
  {
    float a0 = redq(plh0), a1 = redq(plh1), a2 = redq(plv0), a3 = redq(plv1);
    float a4 = redq(pghx), a5 = redq(pgvx), a6 = redq(pV), a7 = redq(pH);
    if (q == 0) {
      int col = w * 16 + n;
      sQPs[0][col] = a0; sQPs[1][col] = a1; sQPs[2][col] = a2; sQPs[3][col] = a3;
      sQPs[4][col] = a4; sQPs[5][col] = a5; sQPs[6][col] = a6; sQPs[7][col] = a7;
      sQPs[8][col] = un0; sQPs[9][col] = un1;
    }
  }
  __syncthreads();   // barrier #2: scalars ready
  if (w != 0 && w != 2) return;

  // ====== QP tail: waves 0,2 (SIMD0/SIMD2), 64 full lanes = 64 elems ======
  const int col = (w >> 1) * 64 + lane;
  const int e = blockIdx.x * 128 + col;
  float gh0 = sQPs[0][col], gh1 = sQPs[1][col];
  float gv0 = sQPs[2][col], gv1 = sQPs[3][col];
  float ghx = sQPs[4][col], gvx = sQPs[5][col];
  float V   = 0.5f * sQPs[6][col];
  float H   = sQPs[7][col] + sC[C_HB4];
  un0 = sQPs[8][col]; un1 = sQPs[9][col];
  out[98304 + e]  = V;
  out[163840 + e] = H;

  const float im = 1.0f / 1.2f;
  const float sg = 1e-6f;

  float lo0 = ghx - H;
  float hi1 = gvx - V;
  float lo2 = ghx * im - H;
  float hi3 = gvx * im - V;
  float nq0 = 2.f * un0, nq1 = 2.f * un1;   // -q

  const float d  = 2.f + sg;
  const float rd = 1.f / d;
  const float al = 1.f + im * im;
  const float be = al * (1.f - rd);
  float S00 = be * (gh0 * gh0 + gv0 * gv0) + d;
  float S11 = be * (gh1 * gh1 + gv1 * gv1) + d;
  float S01 = be * (gh0 * gh1 + gv0 * gv1);
  float idet = 1.f / (S00 * S11 - S01 * S01);
  float i00 = S11 * idet, i11 = S00 * idet, i01 = -S01 * idet;

  float X0 = 0.f, X1 = 0.f, X2 = 0.f, X3 = 0.f, X4 = 0.f, X5 = 0.f;
  float Z[8] = {0.f, 0.f, 0.f, 0.f, 0.f, 0.f, 0.f, 0.f};
  float Y[8] = {0.f, 0.f, 0.f, 0.f, 0.f, 0.f, 0.f, 0.f};

  // sg*X proximal terms dropped from rhs: shifts the fixed point by O(1e-6).
#pragma unroll 1
  for (int it = 0; it < 80; ++it) {
    float t0 = Z[0] - Y[0], t1 = Z[1] - Y[1], t2 = Z[2] - Y[2], t3 = Z[3] - Y[3];
    float t4 = Z[4] - Y[4], t5 = Z[5] - Y[5], t6 = Z[6] - Y[6], t7 = Z[7] - Y[7];
    float tauh = t0 + im * t2, tauv = t1 + im * t3;
    float b0 = nq0 + gh0 * tauh + gv0 * tauv;
    float b1 = nq1 + gh1 * tauh + gv1 * tauv;
    float b2 = -100.f - t1 + t4;
    float b3 = -100.f - t3 + t5;
    float b4 = -50.f + t0 + t6;
    float b5 = -50.f + t2 + t7;
    float pp = b2 + im * b3;
    float s2 = b4 + im * b5;
    float cb0 = gh0 * s2 - gv0 * pp;
    float cb1 = gh1 * s2 - gv1 * pp;
    float u0b = b0 - cb0 * rd;
    float u1b = b1 - cb1 * rd;
    X0 = i00 * u0b + i01 * u1b;
    X1 = i01 * u0b + i11 * u1b;
    float gdH = gh0 * X0 + gh1 * X1;
    float gdV = gv0 * X0 + gv1 * X1;
    X2 = (b2 + gdV) * rd;
    X3 = (b3 + im * gdV) * rd;
    X4 = (b4 - gdH) * rd;
    X5 = (b5 - im * gdH) * rd;
    float zt0 = gdH + X4;
    float zt1 = gdV - X2;
    float zt2 = gdH * im + X5;
    float zt3 = gdV * im - X3;

    float v, zn;
    v = zt0 + Y[0]; zn = fmaxf(v, lo0); Y[0] += zt0 - zn; Z[0] = zn;
    v = zt1 + Y[1]; zn = fminf(v, hi1); Y[1] += zt1 - zn; Z[1] = zn;
    v = zt2 + Y[2]; zn = fmaxf(v, lo2); Y[2] += zt2 - zn; Z[2] = zn;
    v = zt3 + Y[3]; zn = fminf(v, hi3); Y[3] += zt3 - zn; Z[3] = zn;
    v = X2 + Y[4];  zn = fmaxf(v, 0.f); Y[4] += X2 - zn;  Z[4] = zn;
    v = X3 + Y[5];  zn = fmaxf(v, 0.f); Y[5] += X3 - zn;  Z[5] = zn;
    v = X4 + Y[6];  zn = fmaxf(v, 0.f); Y[6] += X4 - zn;  Z[6] = zn;
    v = X5 + Y[7];  zn = fmaxf(v, 0.f); Y[7] += X5 - zn;  Z[7] = zn;
  }

  float relax = 0.5f * (X2 + X3);
  const float cc = 0.5f * (1.f + im);
  float Vdot = cc * (gv0 * X0 + gv1 * X1 - gvx);
  float Hdot = cc * (gh0 * X0 + gh1 * X1 - ghx);

  f32x2 uo; uo[0] = X0; uo[1] = X1;
  *(f32x2*)&out[2 * e] = uo;
  out[65536 + e]  = relax;
  out[131072 + e] = Vdot;
  out[196608 + e] = Hdot;
}

extern "C" void kernel_launch(void* const* d_in, const int* in_sizes, int n_in,
                              void* d_out, int out_size, void* d_ws, size_t ws_size,
                              hipStream_t stream) {
  (void)in_sizes; (void)n_in; (void)out_size; (void)ws_size;
  float* out = (float*)d_out;
  _Float16* wsp = (_Float16*)d_ws;
  prep_kernel<<<16, 256, 0, stream>>>(
      d_in[0], d_in[1], d_in[3], d_in[5], d_in[7], d_in[9],
      d_in[2], d_in[4], d_in[6], d_in[8], d_in[10], d_in[11], d_in[12],
      d_in[13], d_in[14], wsp);
  main_kernel<<<256, 512, 0, stream>>>(d_in[0], wsp, out);
}

// Round 4
// 106.450 us; speedup vs baseline: 1.1728x; 1.0109x over previous
//
#include <hip/hip_runtime.h>
#include <hip/hip_bf16.h>
#include <math.h>

typedef _Float16 f16x8 __attribute__((ext_vector_type(8)));
typedef _Float16 f16x4 __attribute__((ext_vector_type(4)));
typedef float    f32x4 __attribute__((ext_vector_type(4)));
typedef float    f32x2 __attribute__((ext_vector_type(2)));

__device__ __forceinline__ float ldin(const void* p, int i, int f32f) {
  return f32f ? ((const float*)p)[i]
              : __bfloat162float(((const __hip_bfloat16*)p)[i]);
}

__device__ __forceinline__ f32x4 MFMA(f16x8 a, f16x8 b, f32x4 c) {
  return __builtin_amdgcn_mfma_f32_16x16x32_f16(a, b, c, 0, 0, 0);
}

__device__ __forceinline__ float tanh_fast(float x) {
  float e = __expf(2.f * x);
  return 1.f - 2.f * __builtin_amdgcn_rcpf(e + 1.f);
}

__device__ __forceinline__ float redq(float v) {
  v += __shfl_xor(v, 16, 64);
  v += __shfl_xor(v, 32, 64);
  return v;
}

// fragment-linear index: (h,k) -> slot; A/B-frag reads lane-contiguous 16B.
__device__ __forceinline__ int widx(int h, int k) {
  return ((h >> 4) << 10) + ((k >> 5) << 9) + (((k >> 3) & 3) << 7) + ((h & 15) << 3) + (k & 7);
}

// ---- ws layout (f16 units) ----
#define OFF_VW2   0
#define OFF_VW2T  4096
#define OFF_HW2   8192
#define OFF_HW2T  12288
#define OFF_HW3   16384
#define OFF_HW3T  20480
#define OFF_W1V   24576   // packed l1 A-frags: per ht: q0=Whi, q1=Whi, q2=Wlo|0, q3=0
#define OFF_W1H   26624
// f32 constants region (at f16-offset 28672 = byte 57344):
#define CF_BASE   28672
#define C_WGV0 0
#define C_WGV1 64
#define C_WGH0 128
#define C_WGH1 192
#define C_VB1  256
#define C_VB2  320
#define C_HB1  384
#define C_HB2  448
#define C_HB3  512
#define C_W4   576
#define C_K    640
#define C_HB4  656
#define C_FLAG 657
#define C_N    658

// ===========================================================================
// Prep: dtype detection + fragment-linear fp16 panels (+transposes) + packed
// layer-1 A-frags + all f32 constants into ws. Runs once (16 blocks).
// ===========================================================================
__global__ __launch_bounds__(256) void prep_kernel(
    const void* px, const void* pVW1, const void* pVW2,
    const void* pHW1, const void* pHW2, const void* pHW3,
    const void* pVb1, const void* pVb2, const void* pHb1, const void* pHb2,
    const void* pHb3, const void* pHW4, const void* pHb4,
    const void* pG0, const void* pK, _Float16* wsp)
{
  __shared__ int sCnt;
  const int tid = threadIdx.x;
  if (tid == 0) sCnt = 0;
  __syncthreads();
  {
    const unsigned short* xb = (const unsigned short*)px;
    int good = 0;
#pragma unroll
    for (int i = 0; i < 2; ++i) {
      int ex = (xb[tid * 2 + i] >> 7) & 0xFF;
      good += (ex >= 97 && ex <= 157) ? 1 : 0;
    }
    atomicAdd(&sCnt, good);
  }
  __syncthreads();
  const int f32f = (sCnt >= 435) ? 0 : 1;   // >=85% of 512 sane -> bf16 inputs

  const int t = blockIdx.x * 256 + tid;     // 0..4095
  int h = t >> 6, k = t & 63;
  int fw = widx(h, k), tw = widx(k, h);
  _Float16 v;
  v = (_Float16)ldin(pVW2, t, f32f); wsp[OFF_VW2 + fw] = v; wsp[OFF_VW2T + tw] = v;
  v = (_Float16)ldin(pHW2, t, f32f); wsp[OFF_HW2 + fw] = v; wsp[OFF_HW2T + tw] = v;
  v = (_Float16)ldin(pHW3, t, f32f); wsp[OFF_HW3 + fw] = v; wsp[OFF_HW3T + tw] = v;
  if (t < 512) {
    // packed layer-1 A-frags: element (h = t>>3, j = t&7)
    int hh = t >> 3, j = t & 7;
    int base = ((hh >> 4) << 9) + ((hh & 15) << 3) + j;   // ht*512 + mm*8 + j
    float f = ldin(pVW1, t, f32f); _Float16 hi = (_Float16)f;
    _Float16 lo = f32f ? (_Float16)(f - (float)hi) : (_Float16)0.f;
    wsp[OFF_W1V + base]       = hi;
    wsp[OFF_W1V + base + 128] = hi;
    wsp[OFF_W1V + base + 256] = lo;
    wsp[OFF_W1V + base + 384] = (_Float16)0.f;
    f = ldin(pHW1, t, f32f); hi = (_Float16)f;
    lo = f32f ? (_Float16)(f - (float)hi) : (_Float16)0.f;
    wsp[OFF_W1H + base]       = hi;
    wsp[OFF_W1H + base + 128] = hi;
    wsp[OFF_W1H + base + 256] = lo;
    wsp[OFF_W1H + base + 384] = (_Float16)0.f;
  }
  if (blockIdx.x == 0) {
    float* wsF = (float*)(wsp + CF_BASE);
    if (tid < 64) {
      float a0 = 0.f, a1 = 0.f, b0 = 0.f, b1 = 0.f;
#pragma unroll
      for (int nn = 0; nn < 8; ++nn) {
        float g0 = ldin(pG0, 2 * nn, f32f), g1 = ldin(pG0, 2 * nn + 1, f32f);
        float wv = ldin(pVW1, tid * 8 + nn, f32f), wh = ldin(pHW1, tid * 8 + nn, f32f);
        a0 += wv * g0; a1 += wv * g1; b0 += wh * g0; b1 += wh * g1;
      }
      wsF[C_WGV0 + tid] = a0; wsF[C_WGV1 + tid] = a1;
      wsF[C_WGH0 + tid] = b0; wsF[C_WGH1 + tid] = b1;
      wsF[C_VB1 + tid] = ldin(pVb1, tid, f32f);
      wsF[C_VB2 + tid] = ldin(pVb2, tid, f32f);
      wsF[C_HB1 + tid] = ldin(pHb1, tid, f32f);
      wsF[C_HB2 + tid] = ldin(pHb2, tid, f32f);
      wsF[C_HB3 + tid] = ldin(pHb3, tid, f32f);
      wsF[C_W4  + tid] = ldin(pHW4, tid, f32f);
    }
    if (tid < 16) wsF[C_K + tid] = ldin(pK, tid, f32f);
    if (tid == 0) { wsF[C_HB4] = ldin(pHb4, 0, f32f); ((int*)wsF)[C_FLAG] = f32f; }
  }
}

// ===========================================================================
// Main: 256 blocks x 512 thr (1 block/CU). Each WAVE owns 16 elems and all
// 64 h-rows; V and H nets are hand-interleaved with separate act buffers so
// each paired stage has 2x independent load/MFMA streams and the serial LDS
// round-trip chain is 5 deep (was 8). Two barriers total. QP tail: waves 0,2
// (SIMD0/SIMD2) run the Schur ADMM for 64 elems each on full 64 lanes, with
// f32x2-packed math (v_pk_* candidates; per-component identical results).
// ===========================================================================
__global__ __launch_bounds__(512, 1) void main_kernel(
    const void* px, const _Float16* wsp, float* out)
{
  __shared__ __align__(16) _Float16 sAct[16][1024];   // [wave][V|H]
  __shared__ __align__(16) float sQPs[10][128];
  __shared__ __align__(16) float sC[C_N];

  const int tid = threadIdx.x, lane = tid & 63, w = tid >> 6;
  const int n = lane & 15, q = lane >> 4;
  const int e0 = blockIdx.x * 128 + w * 16;

  const float* cf = (const float*)(wsp + CF_BASE);
  for (int i = tid; i < C_N; i += 512) sC[i] = cf[i];
  const int f32f = ((const int*)cf)[C_FLAG];
  __syncthreads();   // barrier #1: sC ready

  // ---- x row (16B/32B vector load), B-frag K-packed + u_nom ----
  float xv[8];
  if (f32f) {
    const f32x4* xp = (const f32x4*)((const float*)px + (e0 + n) * 8);
    f32x4 x0 = xp[0], x1 = xp[1];
#pragma unroll
    for (int j = 0; j < 4; ++j) { xv[j] = x0[j]; xv[4 + j] = x1[j]; }
  } else {
    uint4 u = *(const uint4*)((const unsigned short*)px + (e0 + n) * 8);
    unsigned uu[4] = {u.x, u.y, u.z, u.w};
#pragma unroll
    for (int j = 0; j < 4; ++j) {
      xv[2 * j]     = __uint_as_float(uu[j] << 16);
      xv[2 * j + 1] = __uint_as_float(uu[j] & 0xffff0000u);
    }
  }
  float un0 = 0.f, un1 = 0.f;
  f16x8 xb;
#pragma unroll
  for (int j = 0; j < 8; ++j) {
    _Float16 hh = (_Float16)xv[j];
    float lo = xv[j] - (float)hh;
    xb[j] = (q == 1) ? (_Float16)lo : ((q == 3) ? (_Float16)0.f : hh);
    un0 -= xv[j] * sC[C_K + 2 * j];
    un1 -= xv[j] * sC[C_K + 2 * j + 1];
  }

  _Float16* bufV = sAct[2 * w];
  _Float16* bufH = sAct[2 * w + 1];

  // Paired 64x64 stage: both nets' A-frag global loads issued first, then
  // both B ds_reads, then both MFMA groups -> 2x ILP per stage.
  auto gemm64x2 = [&](int poffV, int poffH, f32x4* accV, f32x4* accH) {
    f16x8 aV[8], aH[8];
#pragma unroll
    for (int i = 0; i < 8; ++i)
      aV[i] = *(const f16x8*)(wsp + poffV + i * 512 + lane * 8);
#pragma unroll
    for (int i = 0; i < 8; ++i)
      aH[i] = *(const f16x8*)(wsp + poffH + i * 512 + lane * 8);
    f16x8 bV0 = *(const f16x8*)(bufV + lane * 8);
    f16x8 bV1 = *(const f16x8*)(bufV + 512 + lane * 8);
    f16x8 bH0 = *(const f16x8*)(bufH + lane * 8);
    f16x8 bH1 = *(const f16x8*)(bufH + 512 + lane * 8);
#pragma unroll
    for (int ht = 0; ht < 4; ++ht) {
      f32x4 c = {0.f, 0.f, 0.f, 0.f};
      c = MFMA(aV[2 * ht], bV0, c);
      accV[ht] = MFMA(aV[2 * ht + 1], bV1, c);
      f32x4 d = {0.f, 0.f, 0.f, 0.f};
      d = MFMA(aH[2 * ht], bH0, d);
      accH[ht] = MFMA(aH[2 * ht + 1], bH1, d);
    }
  };
  auto gemm64 = [&](int poff, const _Float16* b, f32x4* acc) {
    f16x8 a[8];
#pragma unroll
    for (int i = 0; i < 8; ++i)
      a[i] = *(const f16x8*)(wsp + poff + i * 512 + lane * 8);
    f16x8 b0 = *(const f16x8*)(b + lane * 8);
    f16x8 b1 = *(const f16x8*)(b + 512 + lane * 8);
#pragma unroll
    for (int ht = 0; ht < 4; ++ht) {
      f32x4 c = {0.f, 0.f, 0.f, 0.f};
      c = MFMA(a[2 * ht], b0, c);
      acc[ht] = MFMA(a[2 * ht + 1], b1, c);
    }
  };
  auto l1gemm2 = [&](f32x4* accV, f32x4* accH) {
    f16x8 aV[4], aH[4];
#pragma unroll
    for (int ht = 0; ht < 4; ++ht)
      aV[ht] = *(const f16x8*)(wsp + OFF_W1V + ht * 512 + lane * 8);
#pragma unroll
    for (int ht = 0; ht < 4; ++ht)
      aH[ht] = *(const f16x8*)(wsp + OFF_W1H + ht * 512 + lane * 8);
#pragma unroll
    for (int ht = 0; ht < 4; ++ht) {
      f32x4 c = {0.f, 0.f, 0.f, 0.f};
      accV[ht] = MFMA(aV[ht], xb, c);   // Whi*xh + Whi*xl + Wlo*xh
      f32x4 d = {0.f, 0.f, 0.f, 0.f};
      accH[ht] = MFMA(aH[ht], xb, d);
    }
  };
  auto wst = [&](const f32x4* vals, _Float16* b) {
#pragma unroll
    for (int ht = 0; ht < 4; ++ht) {
      int aw = ((ht >> 1) << 9) + (((ht & 1) * 2 + (q >> 1)) << 7) + n * 8 + ((q & 1) << 2);
      f16x4 vh;
#pragma unroll
      for (int r = 0; r < 4; ++r) vh[r] = (_Float16)vals[ht][r];
      *(f16x4*)(b + aw) = vh;
    }
  };

  f32x4 accV[4], accH[4], tvV[4], tvH[4];
  f32x4 z1V[4], d1V[4], z1H[4], d1H[4], d2H[4];

  // ===== S1: layer-1 both nets =====
  l1gemm2(accV, accH);
#pragma unroll
  for (int ht = 0; ht < 4; ++ht) {
    int hb = ht * 16 + q * 4;
    f32x4 bV = *(const f32x4*)&sC[C_VB1 + hb];
    f32x4 bH = *(const f32x4*)&sC[C_HB1 + hb];
    z1V[ht] = accV[ht]; z1H[ht] = accH[ht];
#pragma unroll
    for (int r = 0; r < 4; ++r) {
      float t = tanh_fast(z1V[ht][r] + bV[r]);
      tvV[ht][r] = t; d1V[ht][r] = 1.f - t * t;
      t = tanh_fast(z1H[ht][r] + bH[r]);
      tvH[ht][r] = t; d1H[ht][r] = 1.f - t * t;
    }
  }
  wst(tvV, bufV); wst(tvH, bufH);

  // ===== S2: layer-2 both nets =====
  gemm64x2(OFF_VW2, OFF_HW2, accV, accH);
  float pV = 0.f;
#pragma unroll
  for (int ht = 0; ht < 4; ++ht) {
    int hb = ht * 16 + q * 4;
    f32x4 bV = *(const f32x4*)&sC[C_VB2 + hb];
    f32x4 bH = *(const f32x4*)&sC[C_HB2 + hb];
#pragma unroll
    for (int r = 0; r < 4; ++r) {
      float t = tanh_fast(accV[ht][r] + bV[r]);
      pV += t * t;
      tvV[ht][r] = t * (1.f - t * t);          // t2 * d2
      t = tanh_fast(accH[ht][r] + bH[r]);
      tvH[ht][r] = t; d2H[ht][r] = 1.f - t * t;
    }
  }
  wst(tvV, bufV); wst(tvH, bufH);

  // ===== S3: V bwd (W2^T) + H layer-3 (W3) =====
  gemm64x2(OFF_VW2T, OFF_HW3, accV, accH);
  float pgvx = 0.f, plv0 = 0.f, plv1 = 0.f, pH = 0.f;
#pragma unroll
  for (int ht = 0; ht < 4; ++ht) {
    int hb = ht * 16 + q * 4;
    f32x4 g0 = *(const f32x4*)&sC[C_WGV0 + hb];
    f32x4 g1 = *(const f32x4*)&sC[C_WGV1 + hb];
    f32x4 bH = *(const f32x4*)&sC[C_HB3 + hb];
    f32x4 w4 = *(const f32x4*)&sC[C_W4 + hb];
#pragma unroll
    for (int r = 0; r < 4; ++r) {
      float wt = accV[ht][r] * d1V[ht][r];
      pgvx += wt * z1V[ht][r];
      plv0 += wt * g0[r]; plv1 += wt * g1[r];
      float t = tanh_fast(accH[ht][r] + bH[r]);
      pH += t * w4[r];
      tvH[ht][r] = w4[r] * (1.f - t * t);      // v4
    }
  }
  wst(tvH, bufH);

  // ===== S4: H bwd (W3^T) =====
  gemm64(OFF_HW3T, bufH, accH);                // v3
#pragma unroll
  for (int ht = 0; ht < 4; ++ht)
#pragma unroll
    for (int r = 0; r < 4; ++r) tvH[ht][r] = accH[ht][r] * d2H[ht][r];   // bb
  wst(tvH, bufH);

  // ===== S5: H bwd (W2^T) =====
  gemm64(OFF_HW2T, bufH, accH);                // v2
  float pghx = 0.f, plh0 = 0.f, plh1 = 0.f;
#pragma unroll
  for (int ht = 0; ht < 4; ++ht) {
    int hb = ht * 16 + q * 4;
    f32x4 g0 = *(const f32x4*)&sC[C_WGH0 + hb];
    f32x4 g1 = *(const f32x4*)&sC[C_WGH1 + hb];
#pragma unroll
    for (int r = 0; r < 4; ++r) {
      float wt = accH[ht][r] * d1H[ht][r];
      pghx += wt * z1H[ht][r];
      plh0 += wt * g0[r]; plh1 += wt * g1[r];
    }
  }

  // ---- per-element scalars: reduce over q, hand off via LDS transpose ----
  {
    float a0 = redq(plh0), a1 = redq(plh1), a2 = redq(plv0), a3 = redq(plv1);
    float a4 = redq(pghx), a5 = redq(pgvx), a6 = redq(pV), a7 = redq(pH);
    if (q == 0) {
      int col = w * 16 + n;
      sQPs[0][col] = a0; sQPs[1][col] = a1; sQPs[2][col] = a2; sQPs[3][col] = a3;
      sQPs[4][col] = a4; sQPs[5][col] = a5; sQPs[6][col] = a6; sQPs[7][col] = a7;
      sQPs[8][col] = un0; sQPs[9][col] = un1;
    }
  }
  __syncthreads();   // barrier #2: scalars ready
  if (w != 0 && w != 2) return;

  // ====== QP tail: waves 0,2 (SIMD0/SIMD2), 64 full lanes = 64 elems ======
  const int col = (w >> 1) * 64 + lane;
  const int e = blockIdx.x * 128 + col;
  float gh0 = sQPs[0][col], gh1 = sQPs[1][col];
  float gv0 = sQPs[2][col], gv1 = sQPs[3][col];
  float ghx = sQPs[4][col], gvx = sQPs[5][col];
  float V   = 0.5f * sQPs[6][col];
  float H   = sQPs[7][col] + sC[C_HB4];
  un0 = sQPs[8][col]; un1 = sQPs[9][col];
  out[98304 + e]  = V;
  out[163840 + e] = H;

  const float im = 1.0f / 1.2f;
  const float sg = 1e-6f;
  const float d  = 2.f + sg;
  const float rd = 1.f / d;
  const float al = 1.f + im * im;
  const float be = al * (1.f - rd);
  float S00 = be * (gh0 * gh0 + gv0 * gv0) + d;
  float S11 = be * (gh1 * gh1 + gv1 * gv1) + d;
  float S01 = be * (gh0 * gh1 + gv0 * gv1);
  float idet = 1.f / (S00 * S11 - S01 * S01);

  // packed coefficient pairs
  f32x2 IM2; IM2[0] = 1.f; IM2[1] = im;
  f32x2 ghP; ghP[0] = gh0; ghP[1] = gh1;
  f32x2 gvP; gvP[0] = gv0; gvP[1] = gv1;
  f32x2 gHV0; gHV0[0] = gh0; gHV0[1] = gv0;
  f32x2 gHV1; gHV1[0] = gh1; gHV1[1] = gv1;
  f32x2 iA; iA[0] = S11 * idet;  iA[1] = -S01 * idet;   // (i00, i01)
  f32x2 iB; iB[0] = -S01 * idet; iB[1] = S00 * idet;    // (i01, i11)
  f32x2 nqP; nqP[0] = 2.f * un0; nqP[1] = 2.f * un1;    // -q
  f32x2 loA; loA[0] = ghx - H;      loA[1] = ghx * im - H;   // (lo0, lo2)
  f32x2 hiB; hiB[0] = gvx - V;      hiB[1] = gvx * im - V;   // (hi1, hi3)

  // state pairs: A=(Z0,Z2) B=(Z1,Z3) C=(Z4,Z5) D=(Z6,Z7)
  f32x2 ZA = {0.f, 0.f}, ZB = {0.f, 0.f}, ZC = {0.f, 0.f}, ZD = {0.f, 0.f};
  f32x2 YA = {0.f, 0.f}, YB = {0.f, 0.f}, YC = {0.f, 0.f}, YD = {0.f, 0.f};
  f32x2 X01 = {0.f, 0.f}, XP = {0.f, 0.f}, XS = {0.f, 0.f};

  // sg*X proximal terms dropped from rhs: shifts the fixed point by O(1e-6).
#pragma unroll 1
  for (int it = 0; it < 80; ++it) {
    f32x2 tA = ZA - YA, tB = ZB - YB, tC = ZC - YC, tD = ZD - YD;
    float tauh = tA[0] + im * tA[1];
    float tauv = tB[0] + im * tB[1];
    f32x2 bU = nqP + ghP * tauh + gvP * tauv;          // (b0,b1)
    f32x2 bP = tC - tB - 100.f;                        // (b2,b3)
    f32x2 bS = tA + tD - 50.f;                         // (b4,b5)
    float pp = bP[0] + im * bP[1];
    float s2 = bS[0] + im * bS[1];
    f32x2 cb = ghP * s2 - gvP * pp;                    // (cb0,cb1)
    f32x2 ub = bU - cb * rd;                           // (u0b,u1b)
    X01 = iA * ub[0] + iB * ub[1];                     // (X0,X1)
    f32x2 gd = gHV0 * X01[0] + gHV1 * X01[1];          // (gdH,gdV)
    XP = (bP + IM2 * gd[1]) * rd;                      // (X2,X3)
    XS = (bS - IM2 * gd[0]) * rd;                      // (X4,X5)
    f32x2 ztA = IM2 * gd[0] + XS;                      // (zt0,zt2)
    f32x2 ztB = IM2 * gd[1] - XP;                      // (zt1,zt3)

    f32x2 vv, zn;
    vv = ztA + YA; zn[0] = fmaxf(vv[0], loA[0]); zn[1] = fmaxf(vv[1], loA[1]);
    YA += ztA - zn; ZA = zn;
    vv = ztB + YB; zn[0] = fminf(vv[0], hiB[0]); zn[1] = fminf(vv[1], hiB[1]);
    YB += ztB - zn; ZB = zn;
    vv = XP + YC;  zn[0] = fmaxf(vv[0], 0.f);   zn[1] = fmaxf(vv[1], 0.f);
    YC += XP - zn; ZC = zn;
    vv = XS + YD;  zn[0] = fmaxf(vv[0], 0.f);   zn[1] = fmaxf(vv[1], 0.f);
    YD += XS - zn; ZD = zn;
  }

  float relax = 0.5f * (XP[0] + XP[1]);
  const float cc = 0.5f * (1.f + im);
  float Vdot = cc * (gv0 * X01[0] + gv1 * X01[1] - gvx);
  float Hdot = cc * (gh0 * X01[0] + gh1 * X01[1] - ghx);

  f32x2 uo; uo[0] = X01[0]; uo[1] = X01[1];
  *(f32x2*)&out[2 * e] = uo;
  out[65536 + e]  = relax;
  out[131072 + e] = Vdot;
  out[196608 + e] = Hdot;
}

extern "C" void kernel_launch(void* const* d_in, const int* in_sizes, int n_in,
                              void* d_out, int out_size, void* d_ws, size_t ws_size,
                              hipStream_t stream) {
  (void)in_sizes; (void)n_in; (void)out_size; (void)ws_size;
  float* out = (float*)d_out;
  _Float16* wsp = (_Float16*)d_ws;
  prep_kernel<<<16, 256, 0, stream>>>(
      d_in[0], d_in[1], d_in[3], d_in[5], d_in[7], d_in[9],
      d_in[2], d_in[4], d_in[6], d_in[8], d_in[10], d_in[11], d_in[12],
      d_in[13], d_in[14], wsp);
  main_kernel<<<256, 512, 0, stream>>>(d_in[0], wsp, out);
}

// Round 5
// 104.587 us; speedup vs baseline: 1.1937x; 1.0178x over previous
//
#include <hip/hip_runtime.h>
#include <hip/hip_bf16.h>
#include <math.h>

typedef _Float16 f16x8 __attribute__((ext_vector_type(8)));
typedef _Float16 f16x4 __attribute__((ext_vector_type(4)));
typedef float    f32x4 __attribute__((ext_vector_type(4)));
typedef float    f32x2 __attribute__((ext_vector_type(2)));

__device__ __forceinline__ float ldin(const void* p, int i, int f32f) {
  return f32f ? ((const float*)p)[i]
              : __bfloat162float(((const __hip_bfloat16*)p)[i]);
}

__device__ __forceinline__ f32x4 MFMA(f16x8 a, f16x8 b, f32x4 c) {
  return __builtin_amdgcn_mfma_f32_16x16x32_f16(a, b, c, 0, 0, 0);
}

__device__ __forceinline__ float tanh_fast(float x) {
  float e = __expf(2.f * x);
  return 1.f - 2.f * __builtin_amdgcn_rcpf(e + 1.f);
}

__device__ __forceinline__ float redq(float v) {
  v += __shfl_xor(v, 16, 64);
  v += __shfl_xor(v, 32, 64);
  return v;
}

// ---- ws layout (f16 units) ----
// 6 consecutive 4096-elem panels: VW2, VW2T, HW2, HW2T, HW3, HW3T
#define OFF_VW2   0
#define OFF_VW2T  4096
#define OFF_HW2   8192
#define OFF_HW2T  12288
#define OFF_HW3   16384
#define OFF_HW3T  20480
#define OFF_W1V   24576   // packed l1 A-frags: per ht: q0=Whi, q1=Whi, q2=Wlo|0, q3=0
#define OFF_W1H   26624
// f32 constants region (at f16-offset 28672 = byte 57344):
#define CF_BASE   28672
#define C_WGV0 0
#define C_WGV1 64
#define C_WGH0 128
#define C_WGH1 192
#define C_VB1  256
#define C_VB2  320
#define C_HB1  384
#define C_HB2  448
#define C_HB3  512
#define C_W4   576
#define C_K    640
#define C_HB4  656
#define C_FLAG 657
#define C_N    658

// ===========================================================================
// Prep (gather version): every thread owns 8 CONSECUTIVE f16 slots of a
// destination panel -> one coalesced 16B store. Sources are gathered:
// fwd panels = 8 contiguous elems (vector load); transposed = 8 stride-64
// scalars (L2-hot, matrices are 8-16KB). Replaces the old 2B-scatter
// transpose that made prep ~8us. 14 work blocks + 1 constants block.
// ===========================================================================
__global__ __launch_bounds__(256) void prep_kernel(
    const void* px, const void* pVW1, const void* pVW2,
    const void* pHW1, const void* pHW2, const void* pHW3,
    const void* pVb1, const void* pVb2, const void* pHb1, const void* pHb2,
    const void* pHb3, const void* pHW4, const void* pHb4,
    const void* pG0, const void* pK, _Float16* wsp)
{
  __shared__ int sCnt;
  const int tid = threadIdx.x;
  if (tid == 0) sCnt = 0;
  __syncthreads();
  {
    const unsigned short* xb = (const unsigned short*)px;
    int good = 0;
#pragma unroll
    for (int i = 0; i < 2; ++i) {
      int ex = (xb[tid * 2 + i] >> 7) & 0xFF;
      good += (ex >= 97 && ex <= 157) ? 1 : 0;
    }
    atomicAdd(&sCnt, good);
  }
  __syncthreads();
  const int f32f = (sCnt >= 435) ? 0 : 1;   // >=85% of 512 sane -> bf16 inputs

  // 8 contiguous source elems starting at i0 (i0 % 8 == 0)
  auto ld8 = [&](const void* src, int i0, float* o) {
    if (f32f) {
      f32x4 a = *(const f32x4*)((const float*)src + i0);
      f32x4 b = *(const f32x4*)((const float*)src + i0 + 4);
#pragma unroll
      for (int j = 0; j < 4; ++j) { o[j] = a[j]; o[4 + j] = b[j]; }
    } else {
      uint4 u = *(const uint4*)((const unsigned short*)src + i0);
      unsigned uu[4] = {u.x, u.y, u.z, u.w};
#pragma unroll
      for (int j = 0; j < 4; ++j) {
        o[2 * j]     = __uint_as_float(uu[j] << 16);
        o[2 * j + 1] = __uint_as_float(uu[j] & 0xffff0000u);
      }
    }
  };

  const int bid = blockIdx.x;
  if (bid < 14) {
    const int t = bid * 256 + tid;      // 0..3583
    if (t < 3072) {
      // ---- 64x64 panels: p = 0..5, slot8 s8 = 0..511 ----
      const int p = t >> 9, s8 = t & 511;
      const int ps = p >> 1;
      const void* src = (ps == 0) ? pVW2 : ((ps == 1) ? pHW2 : pHW3);
      // widx inverse for s = s8*8:
      const int h  = ((s8 >> 7) << 4) | (s8 & 15);
      const int k0 = (((s8 >> 6) & 1) << 5) | (((s8 >> 4) & 3) << 3);
      f16x8 v;
      if (p & 1) {
        // transposed panel: slot(h,k) holds M[k][h]
#pragma unroll
        for (int j = 0; j < 8; ++j)
          v[j] = (_Float16)ldin(src, (k0 + j) * 64 + h, f32f);
      } else {
        float o[8];
        ld8(src, h * 64 + k0, o);
#pragma unroll
        for (int j = 0; j < 8; ++j) v[j] = (_Float16)o[j];
      }
      *(f16x8*)(wsp + p * 4096 + s8 * 8) = v;
    } else {
      // ---- packed layer-1 A-frags: idx = ht*512 + qq*128 + mm*8 + j ----
      const int t2 = t - 3072;          // 0..511
      const void* src = (t2 >> 8) ? pHW1 : pVW1;
      const int off = (t2 >> 8) ? OFF_W1H : OFF_W1V;
      const int s8 = t2 & 255;
      const int mm = s8 & 15, qq = (s8 >> 4) & 3, ht = s8 >> 6;
      const int hr = ht * 16 + mm;
      float o[8];
      ld8(src, hr * 8, o);
      f16x8 v;
#pragma unroll
      for (int j = 0; j < 8; ++j) {
        _Float16 hi = (_Float16)o[j];
        v[j] = (qq < 2) ? hi
             : ((qq == 2 && f32f) ? (_Float16)(o[j] - (float)hi) : (_Float16)0.f);
      }
      *(f16x8*)(wsp + off + s8 * 8) = v;
    }
  } else {
    // ---- constants block ----
    float* wsF = (float*)(wsp + CF_BASE);
    if (tid < 64) {
      float a0 = 0.f, a1 = 0.f, b0 = 0.f, b1 = 0.f;
#pragma unroll
      for (int nn = 0; nn < 8; ++nn) {
        float g0 = ldin(pG0, 2 * nn, f32f), g1 = ldin(pG0, 2 * nn + 1, f32f);
        float wv = ldin(pVW1, tid * 8 + nn, f32f), wh = ldin(pHW1, tid * 8 + nn, f32f);
        a0 += wv * g0; a1 += wv * g1; b0 += wh * g0; b1 += wh * g1;
      }
      wsF[C_WGV0 + tid] = a0; wsF[C_WGV1 + tid] = a1;
      wsF[C_WGH0 + tid] = b0; wsF[C_WGH1 + tid] = b1;
      wsF[C_VB1 + tid] = ldin(pVb1, tid, f32f);
      wsF[C_VB2 + tid] = ldin(pVb2, tid, f32f);
      wsF[C_HB1 + tid] = ldin(pHb1, tid, f32f);
      wsF[C_HB2 + tid] = ldin(pHb2, tid, f32f);
      wsF[C_HB3 + tid] = ldin(pHb3, tid, f32f);
      wsF[C_W4  + tid] = ldin(pHW4, tid, f32f);
    }
    if (tid < 16) wsF[C_K + tid] = ldin(pK, tid, f32f);
    if (tid == 0) { wsF[C_HB4] = ldin(pHb4, 0, f32f); ((int*)wsF)[C_FLAG] = f32f; }
  }
}

// ===========================================================================
// Main: 256 blocks x 512 thr (1 block/CU). Each WAVE owns 16 elems and all
// 64 h-rows; V and H nets are hand-interleaved with separate act buffers so
// each paired stage has 2x independent load/MFMA streams and the serial LDS
// round-trip chain is 5 deep (was 8). Two barriers total. QP tail: waves 0,2
// (SIMD0/SIMD2) run the Schur ADMM for 64 elems each on full 64 lanes, with
// f32x2-packed math (v_pk_* candidates; per-component identical results).
// ===========================================================================
__global__ __launch_bounds__(512, 1) void main_kernel(
    const void* px, const _Float16* wsp, float* out)
{
  __shared__ __align__(16) _Float16 sAct[16][1024];   // [wave][V|H]
  __shared__ __align__(16) float sQPs[10][128];
  __shared__ __align__(16) float sC[C_N];

  const int tid = threadIdx.x, lane = tid & 63, w = tid >> 6;
  const int n = lane & 15, q = lane >> 4;
  const int e0 = blockIdx.x * 128 + w * 16;

  const float* cf = (const float*)(wsp + CF_BASE);
  for (int i = tid; i < C_N; i += 512) sC[i] = cf[i];
  const int f32f = ((const int*)cf)[C_FLAG];
  __syncthreads();   // barrier #1: sC ready

  // ---- x row (16B/32B vector load), B-frag K-packed + u_nom ----
  float xv[8];
  if (f32f) {
    const f32x4* xp = (const f32x4*)((const float*)px + (e0 + n) * 8);
    f32x4 x0 = xp[0], x1 = xp[1];
#pragma unroll
    for (int j = 0; j < 4; ++j) { xv[j] = x0[j]; xv[4 + j] = x1[j]; }
  } else {
    uint4 u = *(const uint4*)((const unsigned short*)px + (e0 + n) * 8);
    unsigned uu[4] = {u.x, u.y, u.z, u.w};
#pragma unroll
    for (int j = 0; j < 4; ++j) {
      xv[2 * j]     = __uint_as_float(uu[j] << 16);
      xv[2 * j + 1] = __uint_as_float(uu[j] & 0xffff0000u);
    }
  }
  float un0 = 0.f, un1 = 0.f;
  f16x8 xb;
#pragma unroll
  for (int j = 0; j < 8; ++j) {
    _Float16 hh = (_Float16)xv[j];
    float lo = xv[j] - (float)hh;
    xb[j] = (q == 1) ? (_Float16)lo : ((q == 3) ? (_Float16)0.f : hh);
    un0 -= xv[j] * sC[C_K + 2 * j];
    un1 -= xv[j] * sC[C_K + 2 * j + 1];
  }

  _Float16* bufV = sAct[2 * w];
  _Float16* bufH = sAct[2 * w + 1];

  // Paired 64x64 stage: both nets' A-frag global loads issued first, then
  // both B ds_reads, then both MFMA groups -> 2x ILP per stage.
  auto gemm64x2 = [&](int poffV, int poffH, f32x4* accV, f32x4* accH) {
    f16x8 aV[8], aH[8];
#pragma unroll
    for (int i = 0; i < 8; ++i)
      aV[i] = *(const f16x8*)(wsp + poffV + i * 512 + lane * 8);
#pragma unroll
    for (int i = 0; i < 8; ++i)
      aH[i] = *(const f16x8*)(wsp + poffH + i * 512 + lane * 8);
    f16x8 bV0 = *(const f16x8*)(bufV + lane * 8);
    f16x8 bV1 = *(const f16x8*)(bufV + 512 + lane * 8);
    f16x8 bH0 = *(const f16x8*)(bufH + lane * 8);
    f16x8 bH1 = *(const f16x8*)(bufH + 512 + lane * 8);
#pragma unroll
    for (int ht = 0; ht < 4; ++ht) {
      f32x4 c = {0.f, 0.f, 0.f, 0.f};
      c = MFMA(aV[2 * ht], bV0, c);
      accV[ht] = MFMA(aV[2 * ht + 1], bV1, c);
      f32x4 d = {0.f, 0.f, 0.f, 0.f};
      d = MFMA(aH[2 * ht], bH0, d);
      accH[ht] = MFMA(aH[2 * ht + 1], bH1, d);
    }
  };
  auto gemm64 = [&](int poff, const _Float16* b, f32x4* acc) {
    f16x8 a[8];
#pragma unroll
    for (int i = 0; i < 8; ++i)
      a[i] = *(const f16x8*)(wsp + poff + i * 512 + lane * 8);
    f16x8 b0 = *(const f16x8*)(b + lane * 8);
    f16x8 b1 = *(const f16x8*)(b + 512 + lane * 8);
#pragma unroll
    for (int ht = 0; ht < 4; ++ht) {
      f32x4 c = {0.f, 0.f, 0.f, 0.f};
      c = MFMA(a[2 * ht], b0, c);
      acc[ht] = MFMA(a[2 * ht + 1], b1, c);
    }
  };
  auto l1gemm2 = [&](f32x4* accV, f32x4* accH) {
    f16x8 aV[4], aH[4];
#pragma unroll
    for (int ht = 0; ht < 4; ++ht)
      aV[ht] = *(const f16x8*)(wsp + OFF_W1V + ht * 512 + lane * 8);
#pragma unroll
    for (int ht = 0; ht < 4; ++ht)
      aH[ht] = *(const f16x8*)(wsp + OFF_W1H + ht * 512 + lane * 8);
#pragma unroll
    for (int ht = 0; ht < 4; ++ht) {
      f32x4 c = {0.f, 0.f, 0.f, 0.f};
      accV[ht] = MFMA(aV[ht], xb, c);   // Whi*xh + Whi*xl + Wlo*xh
      f32x4 d = {0.f, 0.f, 0.f, 0.f};
      accH[ht] = MFMA(aH[ht], xb, d);
    }
  };
  auto wst = [&](const f32x4* vals, _Float16* b) {
#pragma unroll
    for (int ht = 0; ht < 4; ++ht) {
      int aw = ((ht >> 1) << 9) + (((ht & 1) * 2 + (q >> 1)) << 7) + n * 8 + ((q & 1) << 2);
      f16x4 vh;
#pragma unroll
      for (int r = 0; r < 4; ++r) vh[r] = (_Float16)vals[ht][r];
      *(f16x4*)(b + aw) = vh;
    }
  };

  f32x4 accV[4], accH[4], tvV[4], tvH[4];
  f32x4 z1V[4], d1V[4], z1H[4], d1H[4], d2H[4];

  // ===== S1: layer-1 both nets =====
  l1gemm2(accV, accH);
#pragma unroll
  for (int ht = 0; ht < 4; ++ht) {
    int hb = ht * 16 + q * 4;
    f32x4 bV = *(const f32x4*)&sC[C_VB1 + hb];
    f32x4 bH = *(const f32x4*)&sC[C_HB1 + hb];
    z1V[ht] = accV[ht]; z1H[ht] = accH[ht];
#pragma unroll
    for (int r = 0; r < 4; ++r) {
      float t = tanh_fast(z1V[ht][r] + bV[r]);
      tvV[ht][r] = t; d1V[ht][r] = 1.f - t * t;
      t = tanh_fast(z1H[ht][r] + bH[r]);
      tvH[ht][r] = t; d1H[ht][r] = 1.f - t * t;
    }
  }
  wst(tvV, bufV); wst(tvH, bufH);

  // ===== S2: layer-2 both nets =====
  gemm64x2(OFF_VW2, OFF_HW2, accV, accH);
  float pV = 0.f;
#pragma unroll
  for (int ht = 0; ht < 4; ++ht) {
    int hb = ht * 16 + q * 4;
    f32x4 bV = *(const f32x4*)&sC[C_VB2 + hb];
    f32x4 bH = *(const f32x4*)&sC[C_HB2 + hb];
#pragma unroll
    for (int r = 0; r < 4; ++r) {
      float t = tanh_fast(accV[ht][r] + bV[r]);
      pV += t * t;
      tvV[ht][r] = t * (1.f - t * t);          // t2 * d2
      t = tanh_fast(accH[ht][r] + bH[r]);
      tvH[ht][r] = t; d2H[ht][r] = 1.f - t * t;
    }
  }
  wst(tvV, bufV); wst(tvH, bufH);

  // ===== S3: V bwd (W2^T) + H layer-3 (W3) =====
  gemm64x2(OFF_VW2T, OFF_HW3, accV, accH);
  float pgvx = 0.f, plv0 = 0.f, plv1 = 0.f, pH = 0.f;
#pragma unroll
  for (int ht = 0; ht < 4; ++ht) {
    int hb = ht * 16 + q * 4;
    f32x4 g0 = *(const f32x4*)&sC[C_WGV0 + hb];
    f32x4 g1 = *(const f32x4*)&sC[C_WGV1 + hb];
    f32x4 bH = *(const f32x4*)&sC[C_HB3 + hb];
    f32x4 w4 = *(const f32x4*)&sC[C_W4 + hb];
#pragma unroll
    for (int r = 0; r < 4; ++r) {
      float wt = accV[ht][r] * d1V[ht][r];
      pgvx += wt * z1V[ht][r];
      plv0 += wt * g0[r]; plv1 += wt * g1[r];
      float t = tanh_fast(accH[ht][r] + bH[r]);
      pH += t * w4[r];
      tvH[ht][r] = w4[r] * (1.f - t * t);      // v4
    }
  }
  wst(tvH, bufH);

  // ===== S4: H bwd (W3^T) =====
  gemm64(OFF_HW3T, bufH, accH);                // v3
#pragma unroll
  for (int ht = 0; ht < 4; ++ht)
#pragma unroll
    for (int r = 0; r < 4; ++r) tvH[ht][r] = accH[ht][r] * d2H[ht][r];   // bb
  wst(tvH, bufH);

  // ===== S5: H bwd (W2^T) =====
  gemm64(OFF_HW2T, bufH, accH);                // v2
  float pghx = 0.f, plh0 = 0.f, plh1 = 0.f;
#pragma unroll
  for (int ht = 0; ht < 4; ++ht) {
    int hb = ht * 16 + q * 4;
    f32x4 g0 = *(const f32x4*)&sC[C_WGH0 + hb];
    f32x4 g1 = *(const f32x4*)&sC[C_WGH1 + hb];
#pragma unroll
    for (int r = 0; r < 4; ++r) {
      float wt = accH[ht][r] * d1H[ht][r];
      pghx += wt * z1H[ht][r];
      plh0 += wt * g0[r]; plh1 += wt * g1[r];
    }
  }

  // ---- per-element scalars: reduce over q, hand off via LDS transpose ----
  {
    float a0 = redq(plh0), a1 = redq(plh1), a2 = redq(plv0), a3 = redq(plv1);
    float a4 = redq(pghx), a5 = redq(pgvx), a6 = redq(pV), a7 = redq(pH);
    if (q == 0) {
      int col = w * 16 + n;
      sQPs[0][col] = a0; sQPs[1][col] = a1; sQPs[2][col] = a2; sQPs[3][col] = a3;
      sQPs[4][col] = a4; sQPs[5][col] = a5; sQPs[6][col] = a6; sQPs[7][col] = a7;
      sQPs[8][col] = un0; sQPs[9][col] = un1;
    }
  }
  __syncthreads();   // barrier #2: scalars ready
  if (w != 0 && w != 2) return;

  // ====== QP tail: waves 0,2 (SIMD0/SIMD2), 64 full lanes = 64 elems ======
  const int col = (w >> 1) * 64 + lane;
  const int e = blockIdx.x * 128 + col;
  float gh0 = sQPs[0][col], gh1 = sQPs[1][col];
  float gv0 = sQPs[2][col], gv1 = sQPs[3][col];
  float ghx = sQPs[4][col], gvx = sQPs[5][col];
  float V   = 0.5f * sQPs[6][col];
  float H   = sQPs[7][col] + sC[C_HB4];
  un0 = sQPs[8][col]; un1 = sQPs[9][col];
  out[98304 + e]  = V;
  out[163840 + e] = H;

  const float im = 1.0f / 1.2f;
  const float sg = 1e-6f;
  const float d  = 2.f + sg;
  const float rd = 1.f / d;
  const float al = 1.f + im * im;
  const float be = al * (1.f - rd);
  float S00 = be * (gh0 * gh0 + gv0 * gv0) + d;
  float S11 = be * (gh1 * gh1 + gv1 * gv1) + d;
  float S01 = be * (gh0 * gh1 + gv0 * gv1);
  float idet = 1.f / (S00 * S11 - S01 * S01);

  // packed coefficient pairs
  f32x2 IM2; IM2[0] = 1.f; IM2[1] = im;
  f32x2 ghP; ghP[0] = gh0; ghP[1] = gh1;
  f32x2 gvP; gvP[0] = gv0; gvP[1] = gv1;
  f32x2 gHV0; gHV0[0] = gh0; gHV0[1] = gv0;
  f32x2 gHV1; gHV1[0] = gh1; gHV1[1] = gv1;
  f32x2 iA; iA[0] = S11 * idet;  iA[1] = -S01 * idet;   // (i00, i01)
  f32x2 iB; iB[0] = -S01 * idet; iB[1] = S00 * idet;    // (i01, i11)
  f32x2 nqP; nqP[0] = 2.f * un0; nqP[1] = 2.f * un1;    // -q
  f32x2 loA; loA[0] = ghx - H;      loA[1] = ghx * im - H;   // (lo0, lo2)
  f32x2 hiB; hiB[0] = gvx - V;      hiB[1] = gvx * im - V;   // (hi1, hi3)

  // state pairs: A=(Z0,Z2) B=(Z1,Z3) C=(Z4,Z5) D=(Z6,Z7)
  f32x2 ZA = {0.f, 0.f}, ZB = {0.f, 0.f}, ZC = {0.f, 0.f}, ZD = {0.f, 0.f};
  f32x2 YA = {0.f, 0.f}, YB = {0.f, 0.f}, YC = {0.f, 0.f}, YD = {0.f, 0.f};
  f32x2 X01 = {0.f, 0.f}, XP = {0.f, 0.f}, XS = {0.f, 0.f};

  // sg*X proximal terms dropped from rhs: shifts the fixed point by O(1e-6).
#pragma unroll 1
  for (int it = 0; it < 80; ++it) {
    f32x2 tA = ZA - YA, tB = ZB - YB, tC = ZC - YC, tD = ZD - YD;
    float tauh = tA[0] + im * tA[1];
    float tauv = tB[0] + im * tB[1];
    f32x2 bU = nqP + ghP * tauh + gvP * tauv;          // (b0,b1)
    f32x2 bP = tC - tB - 100.f;                        // (b2,b3)
    f32x2 bS = tA + tD - 50.f;                         // (b4,b5)
    float pp = bP[0] + im * bP[1];
    float s2 = bS[0] + im * bS[1];
    f32x2 cb = ghP * s2 - gvP * pp;                    // (cb0,cb1)
    f32x2 ub = bU - cb * rd;                           // (u0b,u1b)
    X01 = iA * ub[0] + iB * ub[1];                     // (X0,X1)
    f32x2 gd = gHV0 * X01[0] + gHV1 * X01[1];          // (gdH,gdV)
    XP = (bP + IM2 * gd[1]) * rd;                      // (X2,X3)
    XS = (bS - IM2 * gd[0]) * rd;                      // (X4,X5)
    f32x2 ztA = IM2 * gd[0] + XS;                      // (zt0,zt2)
    f32x2 ztB = IM2 * gd[1] - XP;                      // (zt1,zt3)

    f32x2 vv, zn;
    vv = ztA + YA; zn[0] = fmaxf(vv[0], loA[0]); zn[1] = fmaxf(vv[1], loA[1]);
    YA += ztA - zn; ZA = zn;
    vv = ztB + YB; zn[0] = fminf(vv[0], hiB[0]); zn[1] = fminf(vv[1], hiB[1]);
    YB += ztB - zn; ZB = zn;
    vv = XP + YC;  zn[0] = fmaxf(vv[0], 0.f);   zn[1] = fmaxf(vv[1], 0.f);
    YC += XP - zn; ZC = zn;
    vv = XS + YD;  zn[0] = fmaxf(vv[0], 0.f);   zn[1] = fmaxf(vv[1], 0.f);
    YD += XS - zn; ZD = zn;
  }

  float relax = 0.5f * (XP[0] + XP[1]);
  const float cc = 0.5f * (1.f + im);
  float Vdot = cc * (gv0 * X01[0] + gv1 * X01[1] - gvx);
  float Hdot = cc * (gh0 * X01[0] + gh1 * X01[1] - ghx);

  f32x2 uo; uo[0] = X01[0]; uo[1] = X01[1];
  *(f32x2*)&out[2 * e] = uo;
  out[65536 + e]  = relax;
  out[131072 + e] = Vdot;
  out[196608 + e] = Hdot;
}

extern "C" void kernel_launch(void* const* d_in, const int* in_sizes, int n_in,
                              void* d_out, int out_size, void* d_ws, size_t ws_size,
                              hipStream_t stream) {
  (void)in_sizes; (void)n_in; (void)out_size; (void)ws_size;
  float* out = (float*)d_out;
  _Float16* wsp = (_Float16*)d_ws;
  prep_kernel<<<15, 256, 0, stream>>>(
      d_in[0], d_in[1], d_in[3], d_in[5], d_in[7], d_in[9],
      d_in[2], d_in[4], d_in[6], d_in[8], d_in[10], d_in[11], d_in[12],
      d_in[13], d_in[14], wsp);
  main_kernel<<<256, 512, 0, stream>>>(d_in[0], wsp, out);
}

// Round 7
// 103.830 us; speedup vs baseline: 1.2024x; 1.0073x over previous
//
#include <hip/hip_runtime.h>
#include <hip/hip_bf16.h>
#include <math.h>

typedef _Float16 f16x8 __attribute__((ext_vector_type(8)));
typedef _Float16 f16x4 __attribute__((ext_vector_type(4)));
typedef float    f32x4 __attribute__((ext_vector_type(4)));
typedef float    f32x2 __attribute__((ext_vector_type(2)));

__device__ __forceinline__ float ldin(const void* p, int i, int f32f) {
  return f32f ? ((const float*)p)[i]
              : __bfloat162float(((const __hip_bfloat16*)p)[i]);
}

__device__ __forceinline__ f32x4 MFMA(f16x8 a, f16x8 b, f32x4 c) {
  return __builtin_amdgcn_mfma_f32_16x16x32_f16(a, b, c, 0, 0, 0);
}

__device__ __forceinline__ float tanh_fast(float x) {
  float e = __expf(2.f * x);
  return 1.f - 2.f * __builtin_amdgcn_rcpf(e + 1.f);
}

__device__ __forceinline__ float redq(float v) {
  v += __shfl_xor(v, 16, 64);
  v += __shfl_xor(v, 32, 64);
  return v;
}

// ---- ws layout (f16 units) ----
// 6 consecutive 4096-elem panels: VW2, VW2T, HW2, HW2T, HW3, HW3T
#define OFF_VW2   0
#define OFF_VW2T  4096
#define OFF_HW2   8192
#define OFF_HW2T  12288
#define OFF_HW3   16384
#define OFF_HW3T  20480
#define OFF_W1V   24576   // packed l1 A-frags: per ht: q0=Whi, q1=Whi, q2=Wlo|0, q3=0
#define OFF_W1H   26624
#define W_N       28672   // f16 slots of full panel region (ALL copied to LDS)
// f32 constants region (at f16-offset 28672 = byte 57344):
#define CF_BASE   28672
#define C_WGV0 0
#define C_WGV1 64
#define C_WGH0 128
#define C_WGH1 192
#define C_VB1  256
#define C_VB2  320
#define C_HB1  384
#define C_HB2  448
#define C_HB3  512
#define C_W4   576
#define C_K    640
#define C_HB4  656
#define C_FLAG 657
#define C_N    658

// ===========================================================================
// Prep (gather version): every thread owns 8 CONSECUTIVE f16 slots of a
// destination panel -> one coalesced 16B store. Sources are gathered:
// fwd panels = 8 contiguous elems (vector load); transposed = 8 stride-64
// scalars (L2-hot, matrices are 8-16KB). 14 work blocks + 1 constants block.
// ===========================================================================
__global__ __launch_bounds__(256) void prep_kernel(
    const void* px, const void* pVW1, const void* pVW2,
    const void* pHW1, const void* pHW2, const void* pHW3,
    const void* pVb1, const void* pVb2, const void* pHb1, const void* pHb2,
    const void* pHb3, const void* pHW4, const void* pHb4,
    const void* pG0, const void* pK, _Float16* wsp)
{
  __shared__ int sCnt;
  const int tid = threadIdx.x;
  if (tid == 0) sCnt = 0;
  __syncthreads();
  {
    const unsigned short* xb = (const unsigned short*)px;
    int good = 0;
#pragma unroll
    for (int i = 0; i < 2; ++i) {
      int ex = (xb[tid * 2 + i] >> 7) & 0xFF;
      good += (ex >= 97 && ex <= 157) ? 1 : 0;
    }
    atomicAdd(&sCnt, good);
  }
  __syncthreads();
  const int f32f = (sCnt >= 435) ? 0 : 1;   // >=85% of 512 sane -> bf16 inputs

  // 8 contiguous source elems starting at i0 (i0 % 8 == 0)
  auto ld8 = [&](const void* src, int i0, float* o) {
    if (f32f) {
      f32x4 a = *(const f32x4*)((const float*)src + i0);
      f32x4 b = *(const f32x4*)((const float*)src + i0 + 4);
#pragma unroll
      for (int j = 0; j < 4; ++j) { o[j] = a[j]; o[4 + j] = b[j]; }
    } else {
      uint4 u = *(const uint4*)((const unsigned short*)src + i0);
      unsigned uu[4] = {u.x, u.y, u.z, u.w};
#pragma unroll
      for (int j = 0; j < 4; ++j) {
        o[2 * j]     = __uint_as_float(uu[j] << 16);
        o[2 * j + 1] = __uint_as_float(uu[j] & 0xffff0000u);
      }
    }
  };

  const int bid = blockIdx.x;
  if (bid < 14) {
    const int t = bid * 256 + tid;      // 0..3583
    if (t < 3072) {
      // ---- 64x64 panels: p = 0..5, slot8 s8 = 0..511 ----
      const int p = t >> 9, s8 = t & 511;
      const int ps = p >> 1;
      const void* src = (ps == 0) ? pVW2 : ((ps == 1) ? pHW2 : pHW3);
      // widx inverse for s = s8*8:
      const int h  = ((s8 >> 7) << 4) | (s8 & 15);
      const int k0 = (((s8 >> 6) & 1) << 5) | (((s8 >> 4) & 3) << 3);
      f16x8 v;
      if (p & 1) {
        // transposed panel: slot(h,k) holds M[k][h]
#pragma unroll
        for (int j = 0; j < 8; ++j)
          v[j] = (_Float16)ldin(src, (k0 + j) * 64 + h, f32f);
      } else {
        float o[8];
        ld8(src, h * 64 + k0, o);
#pragma unroll
        for (int j = 0; j < 8; ++j) v[j] = (_Float16)o[j];
      }
      *(f16x8*)(wsp + p * 4096 + s8 * 8) = v;
    } else {
      // ---- packed layer-1 A-frags: idx = ht*512 + qq*128 + mm*8 + j ----
      const int t2 = t - 3072;          // 0..511
      const void* src = (t2 >> 8) ? pHW1 : pVW1;
      const int off = (t2 >> 8) ? OFF_W1H : OFF_W1V;
      const int s8 = t2 & 255;
      const int mm = s8 & 15, qq = (s8 >> 4) & 3, ht = s8 >> 6;
      const int hr = ht * 16 + mm;
      float o[8];
      ld8(src, hr * 8, o);
      f16x8 v;
#pragma unroll
      for (int j = 0; j < 8; ++j) {
        _Float16 hi = (_Float16)o[j];
        v[j] = (qq < 2) ? hi
             : ((qq == 2 && f32f) ? (_Float16)(o[j] - (float)hi) : (_Float16)0.f);
      }
      *(f16x8*)(wsp + off + s8 * 8) = v;
    }
  } else {
    // ---- constants block ----
    float* wsF = (float*)(wsp + CF_BASE);
    if (tid < 64) {
      float a0 = 0.f, a1 = 0.f, b0 = 0.f, b1 = 0.f;
#pragma unroll
      for (int nn = 0; nn < 8; ++nn) {
        float g0 = ldin(pG0, 2 * nn, f32f), g1 = ldin(pG0, 2 * nn + 1, f32f);
        float wv = ldin(pVW1, tid * 8 + nn, f32f), wh = ldin(pHW1, tid * 8 + nn, f32f);
        a0 += wv * g0; a1 += wv * g1; b0 += wh * g0; b1 += wh * g1;
      }
      wsF[C_WGV0 + tid] = a0; wsF[C_WGV1 + tid] = a1;
      wsF[C_WGH0 + tid] = b0; wsF[C_WGH1 + tid] = b1;
      wsF[C_VB1 + tid] = ldin(pVb1, tid, f32f);
      wsF[C_VB2 + tid] = ldin(pVb2, tid, f32f);
      wsF[C_HB1 + tid] = ldin(pHb1, tid, f32f);
      wsF[C_HB2 + tid] = ldin(pHb2, tid, f32f);
      wsF[C_HB3 + tid] = ldin(pHb3, tid, f32f);
      wsF[C_W4  + tid] = ldin(pHW4, tid, f32f);
    }
    if (tid < 16) wsF[C_K + tid] = ldin(pK, tid, f32f);
    if (tid == 0) { wsF[C_HB4] = ldin(pHb4, 0, f32f); ((int*)wsF)[C_FLAG] = f32f; }
  }
}

// ===========================================================================
// Main: 256 blocks x 512 thr (1 block/CU). All weight panels copied ws->LDS
// once per block as a pure linear memcpy (ws is fragment-linear; 57KB = 7
// coalesced 16B rounds/thread, conflict-free), so every A-frag read is a
// conflict-free ds_read_b128 instead of a loaded-L2 global load. (r6 bug:
// copy stopped at 26624 and missed the W1H panel; sW was also 1 panel
// short -> l1gemm2's H reads ran past sW into sAct. Fixed: sW[28672],
// 7 full copy rounds.) Everything else identical to r5.
// ===========================================================================
__global__ __launch_bounds__(512, 1) void main_kernel(
    const void* px, const _Float16* wsp, float* out)
{
  __shared__ __align__(16) _Float16 sW[W_N];          // fragment-linear panels
  __shared__ __align__(16) _Float16 sAct[16][1024];   // [wave][V|H]
  __shared__ __align__(16) float sQPs[10][128];
  __shared__ __align__(16) float sC[C_N];

  const int tid = threadIdx.x, lane = tid & 63, w = tid >> 6;
  const int n = lane & 15, q = lane >> 4;
  const int e0 = blockIdx.x * 128 + w * 16;

  // ---- linear panel copy ws -> LDS (3584 x 16B chunks = 57344 B) ----
  {
    const f16x8* srcv = (const f16x8*)wsp;
    f16x8* dstv = (f16x8*)sW;
#pragma unroll
    for (int rr = 0; rr < 7; ++rr) dstv[rr * 512 + tid] = srcv[rr * 512 + tid];
  }
  const float* cf = (const float*)(wsp + CF_BASE);
  for (int i = tid; i < C_N; i += 512) sC[i] = cf[i];
  const int f32f = ((const int*)cf)[C_FLAG];

  // ---- x row (16B/32B vector load) before barrier: overlaps copy latency ----
  float xv[8];
  if (f32f) {
    const f32x4* xp = (const f32x4*)((const float*)px + (e0 + n) * 8);
    f32x4 x0 = xp[0], x1 = xp[1];
#pragma unroll
    for (int j = 0; j < 4; ++j) { xv[j] = x0[j]; xv[4 + j] = x1[j]; }
  } else {
    uint4 u = *(const uint4*)((const unsigned short*)px + (e0 + n) * 8);
    unsigned uu[4] = {u.x, u.y, u.z, u.w};
#pragma unroll
    for (int j = 0; j < 4; ++j) {
      xv[2 * j]     = __uint_as_float(uu[j] << 16);
      xv[2 * j + 1] = __uint_as_float(uu[j] & 0xffff0000u);
    }
  }
  __syncthreads();   // barrier #1: sW + sC ready

  float un0 = 0.f, un1 = 0.f;
  f16x8 xb;
#pragma unroll
  for (int j = 0; j < 8; ++j) {
    _Float16 hh = (_Float16)xv[j];
    float lo = xv[j] - (float)hh;
    xb[j] = (q == 1) ? (_Float16)lo : ((q == 3) ? (_Float16)0.f : hh);
    un0 -= xv[j] * sC[C_K + 2 * j];
    un1 -= xv[j] * sC[C_K + 2 * j + 1];
  }

  _Float16* bufV = sAct[2 * w];
  _Float16* bufH = sAct[2 * w + 1];

  // Paired 64x64 stage, all-LDS operands: A ds_reads issued first, then both
  // B ds_reads, then both MFMA groups -> 2x ILP per stage.
  auto gemm64x2 = [&](int poffV, int poffH, f32x4* accV, f32x4* accH) {
    f16x8 aV[8], aH[8];
#pragma unroll
    for (int i = 0; i < 8; ++i)
      aV[i] = *(const f16x8*)(sW + poffV + i * 512 + lane * 8);
#pragma unroll
    for (int i = 0; i < 8; ++i)
      aH[i] = *(const f16x8*)(sW + poffH + i * 512 + lane * 8);
    f16x8 bV0 = *(const f16x8*)(bufV + lane * 8);
    f16x8 bV1 = *(const f16x8*)(bufV + 512 + lane * 8);
    f16x8 bH0 = *(const f16x8*)(bufH + lane * 8);
    f16x8 bH1 = *(const f16x8*)(bufH + 512 + lane * 8);
#pragma unroll
    for (int ht = 0; ht < 4; ++ht) {
      f32x4 c = {0.f, 0.f, 0.f, 0.f};
      c = MFMA(aV[2 * ht], bV0, c);
      accV[ht] = MFMA(aV[2 * ht + 1], bV1, c);
      f32x4 d = {0.f, 0.f, 0.f, 0.f};
      d = MFMA(aH[2 * ht], bH0, d);
      accH[ht] = MFMA(aH[2 * ht + 1], bH1, d);
    }
  };
  auto gemm64 = [&](int poff, const _Float16* b, f32x4* acc) {
    f16x8 a[8];
#pragma unroll
    for (int i = 0; i < 8; ++i)
      a[i] = *(const f16x8*)(sW + poff + i * 512 + lane * 8);
    f16x8 b0 = *(const f16x8*)(b + lane * 8);
    f16x8 b1 = *(const f16x8*)(b + 512 + lane * 8);
#pragma unroll
    for (int ht = 0; ht < 4; ++ht) {
      f32x4 c = {0.f, 0.f, 0.f, 0.f};
      c = MFMA(a[2 * ht], b0, c);
      acc[ht] = MFMA(a[2 * ht + 1], b1, c);
    }
  };
  auto l1gemm2 = [&](f32x4* accV, f32x4* accH) {
    f16x8 aV[4], aH[4];
#pragma unroll
    for (int ht = 0; ht < 4; ++ht)
      aV[ht] = *(const f16x8*)(sW + OFF_W1V + ht * 512 + lane * 8);
#pragma unroll
    for (int ht = 0; ht < 4; ++ht)
      aH[ht] = *(const f16x8*)(sW + OFF_W1H + ht * 512 + lane * 8);
#pragma unroll
    for (int ht = 0; ht < 4; ++ht) {
      f32x4 c = {0.f, 0.f, 0.f, 0.f};
      accV[ht] = MFMA(aV[ht], xb, c);   // Whi*xh + Whi*xl + Wlo*xh
      f32x4 d = {0.f, 0.f, 0.f, 0.f};
      accH[ht] = MFMA(aH[ht], xb, d);
    }
  };
  auto wst = [&](const f32x4* vals, _Float16* b) {
#pragma unroll
    for (int ht = 0; ht < 4; ++ht) {
      int aw = ((ht >> 1) << 9) + (((ht & 1) * 2 + (q >> 1)) << 7) + n * 8 + ((q & 1) << 2);
      f16x4 vh;
#pragma unroll
      for (int r = 0; r < 4; ++r) vh[r] = (_Float16)vals[ht][r];
      *(f16x4*)(b + aw) = vh;
    }
  };

  f32x4 accV[4], accH[4], tvV[4], tvH[4];
  f32x4 z1V[4], d1V[4], z1H[4], d1H[4], d2H[4];

  // ===== S1: layer-1 both nets =====
  l1gemm2(accV, accH);
#pragma unroll
  for (int ht = 0; ht < 4; ++ht) {
    int hb = ht * 16 + q * 4;
    f32x4 bV = *(const f32x4*)&sC[C_VB1 + hb];
    f32x4 bH = *(const f32x4*)&sC[C_HB1 + hb];
    z1V[ht] = accV[ht]; z1H[ht] = accH[ht];
#pragma unroll
    for (int r = 0; r < 4; ++r) {
      float t = tanh_fast(z1V[ht][r] + bV[r]);
      tvV[ht][r] = t; d1V[ht][r] = 1.f - t * t;
      t = tanh_fast(z1H[ht][r] + bH[r]);
      tvH[ht][r] = t; d1H[ht][r] = 1.f - t * t;
    }
  }
  wst(tvV, bufV); wst(tvH, bufH);

  // ===== S2: layer-2 both nets =====
  gemm64x2(OFF_VW2, OFF_HW2, accV, accH);
  float pV = 0.f;
#pragma unroll
  for (int ht = 0; ht < 4; ++ht) {
    int hb = ht * 16 + q * 4;
    f32x4 bV = *(const f32x4*)&sC[C_VB2 + hb];
    f32x4 bH = *(const f32x4*)&sC[C_HB2 + hb];
#pragma unroll
    for (int r = 0; r < 4; ++r) {
      float t = tanh_fast(accV[ht][r] + bV[r]);
      pV += t * t;
      tvV[ht][r] = t * (1.f - t * t);          // t2 * d2
      t = tanh_fast(accH[ht][r] + bH[r]);
      tvH[ht][r] = t; d2H[ht][r] = 1.f - t * t;
    }
  }
  wst(tvV, bufV); wst(tvH, bufH);

  // ===== S3: V bwd (W2^T) + H layer-3 (W3) =====
  gemm64x2(OFF_VW2T, OFF_HW3, accV, accH);
  float pgvx = 0.f, plv0 = 0.f, plv1 = 0.f, pH = 0.f;
#pragma unroll
  for (int ht = 0; ht < 4; ++ht) {
    int hb = ht * 16 + q * 4;
    f32x4 g0 = *(const f32x4*)&sC[C_WGV0 + hb];
    f32x4 g1 = *(const f32x4*)&sC[C_WGV1 + hb];
    f32x4 bH = *(const f32x4*)&sC[C_HB3 + hb];
    f32x4 w4 = *(const f32x4*)&sC[C_W4 + hb];
#pragma unroll
    for (int r = 0; r < 4; ++r) {
      float wt = accV[ht][r] * d1V[ht][r];
      pgvx += wt * z1V[ht][r];
      plv0 += wt * g0[r]; plv1 += wt * g1[r];
      float t = tanh_fast(accH[ht][r] + bH[r]);
      pH += t * w4[r];
      tvH[ht][r] = w4[r] * (1.f - t * t);      // v4
    }
  }
  wst(tvH, bufH);

  // ===== S4: H bwd (W3^T) =====
  gemm64(OFF_HW3T, bufH, accH);                // v3
#pragma unroll
  for (int ht = 0; ht < 4; ++ht)
#pragma unroll
    for (int r = 0; r < 4; ++r) tvH[ht][r] = accH[ht][r] * d2H[ht][r];   // bb
  wst(tvH, bufH);

  // ===== S5: H bwd (W2^T) =====
  gemm64(OFF_HW2T, bufH, accH);                // v2
  float pghx = 0.f, plh0 = 0.f, plh1 = 0.f;
#pragma unroll
  for (int ht = 0; ht < 4; ++ht) {
    int hb = ht * 16 + q * 4;
    f32x4 g0 = *(const f32x4*)&sC[C_WGH0 + hb];
    f32x4 g1 = *(const f32x4*)&sC[C_WGH1 + hb];
#pragma unroll
    for (int r = 0; r < 4; ++r) {
      float wt = accH[ht][r] * d1H[ht][r];
      pghx += wt * z1H[ht][r];
      plh0 += wt * g0[r]; plh1 += wt * g1[r];
    }
  }

  // ---- per-element scalars: reduce over q, hand off via LDS transpose ----
  {
    float a0 = redq(plh0), a1 = redq(plh1), a2 = redq(plv0), a3 = redq(plv1);
    float a4 = redq(pghx), a5 = redq(pgvx), a6 = redq(pV), a7 = redq(pH);
    if (q == 0) {
      int col = w * 16 + n;
      sQPs[0][col] = a0; sQPs[1][col] = a1; sQPs[2][col] = a2; sQPs[3][col] = a3;
      sQPs[4][col] = a4; sQPs[5][col] = a5; sQPs[6][col] = a6; sQPs[7][col] = a7;
      sQPs[8][col] = un0; sQPs[9][col] = un1;
    }
  }
  __syncthreads();   // barrier #2: scalars ready
  if (w != 0 && w != 2) return;

  // ====== QP tail: waves 0,2 (SIMD0/SIMD2), 64 full lanes = 64 elems ======
  const int col = (w >> 1) * 64 + lane;
  const int e = blockIdx.x * 128 + col;
  float gh0 = sQPs[0][col], gh1 = sQPs[1][col];
  float gv0 = sQPs[2][col], gv1 = sQPs[3][col];
  float ghx = sQPs[4][col], gvx = sQPs[5][col];
  float V   = 0.5f * sQPs[6][col];
  float H   = sQPs[7][col] + sC[C_HB4];
  un0 = sQPs[8][col]; un1 = sQPs[9][col];
  out[98304 + e]  = V;
  out[163840 + e] = H;

  const float im = 1.0f / 1.2f;
  const float sg = 1e-6f;
  const float d  = 2.f + sg;
  const float rd = 1.f / d;
  const float al = 1.f + im * im;
  const float be = al * (1.f - rd);
  float S00 = be * (gh0 * gh0 + gv0 * gv0) + d;
  float S11 = be * (gh1 * gh1 + gv1 * gv1) + d;
  float S01 = be * (gh0 * gh1 + gv0 * gv1);
  float idet = 1.f / (S00 * S11 - S01 * S01);

  // packed coefficient pairs
  f32x2 IM2; IM2[0] = 1.f; IM2[1] = im;
  f32x2 ghP; ghP[0] = gh0; ghP[1] = gh1;
  f32x2 gvP; gvP[0] = gv0; gvP[1] = gv1;
  f32x2 gHV0; gHV0[0] = gh0; gHV0[1] = gv0;
  f32x2 gHV1; gHV1[0] = gh1; gHV1[1] = gv1;
  f32x2 iA; iA[0] = S11 * idet;  iA[1] = -S01 * idet;   // (i00, i01)
  f32x2 iB; iB[0] = -S01 * idet; iB[1] = S00 * idet;    // (i01, i11)
  f32x2 nqP; nqP[0] = 2.f * un0; nqP[1] = 2.f * un1;    // -q
  f32x2 loA; loA[0] = ghx - H;      loA[1] = ghx * im - H;   // (lo0, lo2)
  f32x2 hiB; hiB[0] = gvx - V;      hiB[1] = gvx * im - V;   // (hi1, hi3)

  // state pairs: A=(Z0,Z2) B=(Z1,Z3) C=(Z4,Z5) D=(Z6,Z7)
  f32x2 ZA = {0.f, 0.f}, ZB = {0.f, 0.f}, ZC = {0.f, 0.f}, ZD = {0.f, 0.f};
  f32x2 YA = {0.f, 0.f}, YB = {0.f, 0.f}, YC = {0.f, 0.f}, YD = {0.f, 0.f};
  f32x2 X01 = {0.f, 0.f}, XP = {0.f, 0.f}, XS = {0.f, 0.f};

  // sg*X proximal terms dropped from rhs: shifts the fixed point by O(1e-6).
#pragma unroll 1
  for (int it = 0; it < 80; ++it) {
    f32x2 tA = ZA - YA, tB = ZB - YB, tC = ZC - YC, tD = ZD - YD;
    float tauh = tA[0] + im * tA[1];
    float tauv = tB[0] + im * tB[1];
    f32x2 bU = nqP + ghP * tauh + gvP * tauv;          // (b0,b1)
    f32x2 bP = tC - tB - 100.f;                        // (b2,b3)
    f32x2 bS = tA + tD - 50.f;                         // (b4,b5)
    float pp = bP[0] + im * bP[1];
    float s2 = bS[0] + im * bS[1];
    f32x2 cb = ghP * s2 - gvP * pp;                    // (cb0,cb1)
    f32x2 ub = bU - cb * rd;                           // (u0b,u1b)
    X01 = iA * ub[0] + iB * ub[1];                     // (X0,X1)
    f32x2 gd = gHV0 * X01[0] + gHV1 * X01[1];          // (gdH,gdV)
    XP = (bP + IM2 * gd[1]) * rd;                      // (X2,X3)
    XS = (bS - IM2 * gd[0]) * rd;                      // (X4,X5)
    f32x2 ztA = IM2 * gd[0] + XS;                      // (zt0,zt2)
    f32x2 ztB = IM2 * gd[1] - XP;                      // (zt1,zt3)

    f32x2 vv, zn;
    vv = ztA + YA; zn[0] = fmaxf(vv[0], loA[0]); zn[1] = fmaxf(vv[1], loA[1]);
    YA += ztA - zn; ZA = zn;
    vv = ztB + YB; zn[0] = fminf(vv[0], hiB[0]); zn[1] = fminf(vv[1], hiB[1]);
    YB += ztB - zn; ZB = zn;
    vv = XP + YC;  zn[0] = fmaxf(vv[0], 0.f);   zn[1] = fmaxf(vv[1], 0.f);
    YC += XP - zn; ZC = zn;
    vv = XS + YD;  zn[0] = fmaxf(vv[0], 0.f);   zn[1] = fmaxf(vv[1], 0.f);
    YD += XS - zn; ZD = zn;
  }

  float relax = 0.5f * (XP[0] + XP[1]);
  const float cc = 0.5f * (1.f + im);
  float Vdot = cc * (gv0 * X01[0] + gv1 * X01[1] - gvx);
  float Hdot = cc * (gh0 * X01[0] + gh1 * X01[1] - ghx);

  f32x2 uo; uo[0] = X01[0]; uo[1] = X01[1];
  *(f32x2*)&out[2 * e] = uo;
  out[65536 + e]  = relax;
  out[131072 + e] = Vdot;
  out[196608 + e] = Hdot;
}

extern "C" void kernel_launch(void* const* d_in, const int* in_sizes, int n_in,
                              void* d_out, int out_size, void* d_ws, size_t ws_size,
                              hipStream_t stream) {
  (void)in_sizes; (void)n_in; (void)out_size; (void)ws_size;
  float* out = (float*)d_out;
  _Float16* wsp = (_Float16*)d_ws;
  prep_kernel<<<15, 256, 0, stream>>>(
      d_in[0], d_in[1], d_in[3], d_in[5], d_in[7], d_in[9],
      d_in[2], d_in[4], d_in[6], d_in[8], d_in[10], d_in[11], d_in[12],
      d_in[13], d_in[14], wsp);
  main_kernel<<<256, 512, 0, stream>>>(d_in[0], wsp, out);
}

// Round 8
// 101.396 us; speedup vs baseline: 1.2312x; 1.0240x over previous
//
#include <hip/hip_runtime.h>
#include <hip/hip_bf16.h>
#include <math.h>

typedef _Float16 f16x8 __attribute__((ext_vector_type(8)));
typedef _Float16 f16x4 __attribute__((ext_vector_type(4)));
typedef float    f32x4 __attribute__((ext_vector_type(4)));
typedef float    f32x2 __attribute__((ext_vector_type(2)));

__device__ __forceinline__ float ldin(const void* p, int i, int f32f) {
  return f32f ? ((const float*)p)[i]
              : __bfloat162float(((const __hip_bfloat16*)p)[i]);
}

__device__ __forceinline__ f32x4 MFMA(f16x8 a, f16x8 b, f32x4 c) {
  return __builtin_amdgcn_mfma_f32_16x16x32_f16(a, b, c, 0, 0, 0);
}

__device__ __forceinline__ float tanh_fast(float x) {
  float e = __expf(2.f * x);
  return 1.f - 2.f * __builtin_amdgcn_rcpf(e + 1.f);
}

__device__ __forceinline__ float redq(float v) {
  v += __shfl_xor(v, 16, 64);
  v += __shfl_xor(v, 32, 64);
  return v;
}

// ---- LDS panel layout (f16 units), fragment-linear ----
// 6 consecutive 4096-elem panels: VW2, VW2T, HW2, HW2T, HW3, HW3T
#define OFF_VW2   0
#define OFF_VW2T  4096
#define OFF_HW2   8192
#define OFF_HW2T  12288
#define OFF_HW3   16384
#define OFF_HW3T  20480
#define OFF_W1V   24576   // packed l1 A-frags: per ht: q0=Whi, q1=Whi, q2=Wlo|0, q3=0
#define OFF_W1H   26624
#define W_N       28672
// f32 constants
#define C_WGV0 0
#define C_WGV1 64
#define C_WGH0 128
#define C_WGH1 192
#define C_VB1  256
#define C_VB2  320
#define C_HB1  384
#define C_HB2  448
#define C_HB3  512
#define C_W4   576
#define C_K    640
#define C_HB4  656
#define C_N    658

// ===========================================================================
// Single fused kernel: 256 blocks x 512 thr (1 block/CU). Per block:
//  (1) dtype detection (1024 exponent samples, r1-verified),
//  (2) gather-build of all fragment-linear weight panels DIRECTLY into LDS
//      (r5-verified gather: fwd = 1 vector load/slot; transposed = 8
//      coalesced-within-wave L2-hot scalars/slot; W1 = row load + qq-pack;
//      7 slots/thread, one 16B ds_write each — no scatter, ~L2-latency cost),
//  (3) per-block sC constants (r1-verified),
//  then r7's main body verbatim: wave owns 16 elems x all 64 h, V/H nets
//  interleaved, zero stage barriers, full-lane ADMM tail on waves 0,2.
// No ws, no prep kernel, ONE launch (saves a dispatch + gap).
// ===========================================================================
__global__ __launch_bounds__(512, 1) void fused_kernel(
    const void* px, const void* pVW1, const void* pVb1, const void* pVW2, const void* pVb2,
    const void* pHW1, const void* pHb1, const void* pHW2, const void* pHb2,
    const void* pHW3, const void* pHb3, const void* pHW4, const void* pHb4,
    const void* pG0, const void* pK, float* out)
{
  __shared__ __align__(16) _Float16 sW[W_N];          // fragment-linear panels
  __shared__ __align__(16) _Float16 sAct[16][1024];   // [wave][V|H]
  __shared__ __align__(16) float sQPs[10][128];
  __shared__ __align__(16) float sC[C_N];
  __shared__ int sCnt;

  const int tid = threadIdx.x, lane = tid & 63, w = tid >> 6;
  const int n = lane & 15, q = lane >> 4;
  const int e0 = blockIdx.x * 128 + w * 16;

  // ---- (1) dtype detection ----
  if (tid == 0) sCnt = 0;
  __syncthreads();
  {
    const unsigned short* xbp = (const unsigned short*)px;
    int good = 0;
#pragma unroll
    for (int i = 0; i < 2; ++i) {
      int ex = (xbp[tid * 2 + i] >> 7) & 0xFF;
      good += (ex >= 97 && ex <= 157) ? 1 : 0;
    }
    atomicAdd(&sCnt, good);
  }
  __syncthreads();
  const int f32f = (sCnt >= 870) ? 0 : 1;   // >=85% of 1024 sane -> bf16 inputs

  // ---- x row (16B/32B vector load): issue early, consumed after barrier ----
  float xv[8];
  if (f32f) {
    const f32x4* xp = (const f32x4*)((const float*)px + (e0 + n) * 8);
    f32x4 x0 = xp[0], x1 = xp[1];
#pragma unroll
    for (int j = 0; j < 4; ++j) { xv[j] = x0[j]; xv[4 + j] = x1[j]; }
  } else {
    uint4 u = *(const uint4*)((const unsigned short*)px + (e0 + n) * 8);
    unsigned uu[4] = {u.x, u.y, u.z, u.w};
#pragma unroll
    for (int j = 0; j < 4; ++j) {
      xv[2 * j]     = __uint_as_float(uu[j] << 16);
      xv[2 * j + 1] = __uint_as_float(uu[j] & 0xffff0000u);
    }
  }

  // 8 contiguous source elems starting at i0 (i0 % 8 == 0)
  auto ld8 = [&](const void* src, int i0, float* o) {
    if (f32f) {
      f32x4 a = *(const f32x4*)((const float*)src + i0);
      f32x4 b = *(const f32x4*)((const float*)src + i0 + 4);
#pragma unroll
      for (int j = 0; j < 4; ++j) { o[j] = a[j]; o[4 + j] = b[j]; }
    } else {
      uint4 u = *(const uint4*)((const unsigned short*)src + i0);
      unsigned uu[4] = {u.x, u.y, u.z, u.w};
#pragma unroll
      for (int j = 0; j < 4; ++j) {
        o[2 * j]     = __uint_as_float(uu[j] << 16);
        o[2 * j + 1] = __uint_as_float(uu[j] & 0xffff0000u);
      }
    }
  };

  // ---- (2) gather-build panels into LDS: 7 slots/thread, 16B store each ----
  {
    // slots 0..3071: 6 panels (p = slot>>9), s8 = tid
    const int s8 = tid & 511;               // == tid for rounds below
    const int h  = ((s8 >> 7) << 4) | (s8 & 15);
    const int k0 = (((s8 >> 6) & 1) << 5) | (((s8 >> 4) & 3) << 3);
#pragma unroll
    for (int p = 0; p < 6; ++p) {
      const void* src = (p < 2) ? pVW2 : ((p < 4) ? pHW2 : pHW3);
      f16x8 v;
      if (p & 1) {
        // transposed panel: slot(h,k) holds M[k][h]; lanes n-consecutive in h
#pragma unroll
        for (int j = 0; j < 8; ++j)
          v[j] = (_Float16)ldin(src, (k0 + j) * 64 + h, f32f);
      } else {
        float o[8];
        ld8(src, h * 64 + k0, o);
#pragma unroll
        for (int j = 0; j < 8; ++j) v[j] = (_Float16)o[j];
      }
      *(f16x8*)(sW + p * 4096 + s8 * 8) = v;
    }
    // slots 3072..3583: packed layer-1 A-frags (512 slots = 512 threads)
    {
      const int t2 = tid;                   // 0..511
      const void* src = (t2 >> 8) ? pHW1 : pVW1;
      const int off = (t2 >> 8) ? OFF_W1H : OFF_W1V;
      const int ss = t2 & 255;
      const int mm = ss & 15, qq = (ss >> 4) & 3, ht = ss >> 6;
      float o[8];
      ld8(src, (ht * 16 + mm) * 8, o);
      f16x8 v;
#pragma unroll
      for (int j = 0; j < 8; ++j) {
        _Float16 hi = (_Float16)o[j];
        v[j] = (qq < 2) ? hi
             : ((qq == 2 && f32f) ? (_Float16)(o[j] - (float)hi) : (_Float16)0.f);
      }
      *(f16x8*)(sW + off + ss * 8) = v;
    }
  }

  // ---- (3) constants into sC ----
  if (tid < 64) {
    float a0 = 0.f, a1 = 0.f, b0 = 0.f, b1 = 0.f;
#pragma unroll
    for (int nn = 0; nn < 8; ++nn) {
      float g0 = ldin(pG0, 2 * nn, f32f), g1 = ldin(pG0, 2 * nn + 1, f32f);
      float wv = ldin(pVW1, tid * 8 + nn, f32f), wh = ldin(pHW1, tid * 8 + nn, f32f);
      a0 += wv * g0; a1 += wv * g1; b0 += wh * g0; b1 += wh * g1;
    }
    sC[C_WGV0 + tid] = a0; sC[C_WGV1 + tid] = a1;
    sC[C_WGH0 + tid] = b0; sC[C_WGH1 + tid] = b1;
    sC[C_VB1 + tid] = ldin(pVb1, tid, f32f);
    sC[C_VB2 + tid] = ldin(pVb2, tid, f32f);
    sC[C_HB1 + tid] = ldin(pHb1, tid, f32f);
    sC[C_HB2 + tid] = ldin(pHb2, tid, f32f);
    sC[C_HB3 + tid] = ldin(pHb3, tid, f32f);
    sC[C_W4  + tid] = ldin(pHW4, tid, f32f);
  }
  if (tid < 16) sC[C_K + tid] = ldin(pK, tid, f32f);
  if (tid == 0) sC[C_HB4] = ldin(pHb4, 0, f32f);

  __syncthreads();   // sW + sC ready

  float un0 = 0.f, un1 = 0.f;
  f16x8 xb;
#pragma unroll
  for (int j = 0; j < 8; ++j) {
    _Float16 hh = (_Float16)xv[j];
    float lo = xv[j] - (float)hh;
    xb[j] = (q == 1) ? (_Float16)lo : ((q == 3) ? (_Float16)0.f : hh);
    un0 -= xv[j] * sC[C_K + 2 * j];
    un1 -= xv[j] * sC[C_K + 2 * j + 1];
  }

  _Float16* bufV = sAct[2 * w];
  _Float16* bufH = sAct[2 * w + 1];

  // Paired 64x64 stage, all-LDS operands.
  auto gemm64x2 = [&](int poffV, int poffH, f32x4* accV, f32x4* accH) {
    f16x8 aV[8], aH[8];
#pragma unroll
    for (int i = 0; i < 8; ++i)
      aV[i] = *(const f16x8*)(sW + poffV + i * 512 + lane * 8);
#pragma unroll
    for (int i = 0; i < 8; ++i)
      aH[i] = *(const f16x8*)(sW + poffH + i * 512 + lane * 8);
    f16x8 bV0 = *(const f16x8*)(bufV + lane * 8);
    f16x8 bV1 = *(const f16x8*)(bufV + 512 + lane * 8);
    f16x8 bH0 = *(const f16x8*)(bufH + lane * 8);
    f16x8 bH1 = *(const f16x8*)(bufH + 512 + lane * 8);
#pragma unroll
    for (int ht = 0; ht < 4; ++ht) {
      f32x4 c = {0.f, 0.f, 0.f, 0.f};
      c = MFMA(aV[2 * ht], bV0, c);
      accV[ht] = MFMA(aV[2 * ht + 1], bV1, c);
      f32x4 d = {0.f, 0.f, 0.f, 0.f};
      d = MFMA(aH[2 * ht], bH0, d);
      accH[ht] = MFMA(aH[2 * ht + 1], bH1, d);
    }
  };
  auto gemm64 = [&](int poff, const _Float16* b, f32x4* acc) {
    f16x8 a[8];
#pragma unroll
    for (int i = 0; i < 8; ++i)
      a[i] = *(const f16x8*)(sW + poff + i * 512 + lane * 8);
    f16x8 b0 = *(const f16x8*)(b + lane * 8);
    f16x8 b1 = *(const f16x8*)(b + 512 + lane * 8);
#pragma unroll
    for (int ht = 0; ht < 4; ++ht) {
      f32x4 c = {0.f, 0.f, 0.f, 0.f};
      c = MFMA(a[2 * ht], b0, c);
      acc[ht] = MFMA(a[2 * ht + 1], b1, c);
    }
  };
  auto l1gemm2 = [&](f32x4* accV, f32x4* accH) {
    f16x8 aV[4], aH[4];
#pragma unroll
    for (int ht = 0; ht < 4; ++ht)
      aV[ht] = *(const f16x8*)(sW + OFF_W1V + ht * 512 + lane * 8);
#pragma unroll
    for (int ht = 0; ht < 4; ++ht)
      aH[ht] = *(const f16x8*)(sW + OFF_W1H + ht * 512 + lane * 8);
#pragma unroll
    for (int ht = 0; ht < 4; ++ht) {
      f32x4 c = {0.f, 0.f, 0.f, 0.f};
      accV[ht] = MFMA(aV[ht], xb, c);   // Whi*xh + Whi*xl + Wlo*xh
      f32x4 d = {0.f, 0.f, 0.f, 0.f};
      accH[ht] = MFMA(aH[ht], xb, d);
    }
  };
  auto wst = [&](const f32x4* vals, _Float16* b) {
#pragma unroll
    for (int ht = 0; ht < 4; ++ht) {
      int aw = ((ht >> 1) << 9) + (((ht & 1) * 2 + (q >> 1)) << 7) + n * 8 + ((q & 1) << 2);
      f16x4 vh;
#pragma unroll
      for (int r = 0; r < 4; ++r) vh[r] = (_Float16)vals[ht][r];
      *(f16x4*)(b + aw) = vh;
    }
  };

  f32x4 accV[4], accH[4], tvV[4], tvH[4];
  f32x4 z1V[4], d1V[4], z1H[4], d1H[4], d2H[4];

  // ===== S1: layer-1 both nets =====
  l1gemm2(accV, accH);
#pragma unroll
  for (int ht = 0; ht < 4; ++ht) {
    int hb = ht * 16 + q * 4;
    f32x4 bV = *(const f32x4*)&sC[C_VB1 + hb];
    f32x4 bH = *(const f32x4*)&sC[C_HB1 + hb];
    z1V[ht] = accV[ht]; z1H[ht] = accH[ht];
#pragma unroll
    for (int r = 0; r < 4; ++r) {
      float t = tanh_fast(z1V[ht][r] + bV[r]);
      tvV[ht][r] = t; d1V[ht][r] = 1.f - t * t;
      t = tanh_fast(z1H[ht][r] + bH[r]);
      tvH[ht][r] = t; d1H[ht][r] = 1.f - t * t;
    }
  }
  wst(tvV, bufV); wst(tvH, bufH);

  // ===== S2: layer-2 both nets =====
  gemm64x2(OFF_VW2, OFF_HW2, accV, accH);
  float pV = 0.f;
#pragma unroll
  for (int ht = 0; ht < 4; ++ht) {
    int hb = ht * 16 + q * 4;
    f32x4 bV = *(const f32x4*)&sC[C_VB2 + hb];
    f32x4 bH = *(const f32x4*)&sC[C_HB2 + hb];
#pragma unroll
    for (int r = 0; r < 4; ++r) {
      float t = tanh_fast(accV[ht][r] + bV[r]);
      pV += t * t;
      tvV[ht][r] = t * (1.f - t * t);          // t2 * d2
      t = tanh_fast(accH[ht][r] + bH[r]);
      tvH[ht][r] = t; d2H[ht][r] = 1.f - t * t;
    }
  }
  wst(tvV, bufV); wst(tvH, bufH);

  // ===== S3: V bwd (W2^T) + H layer-3 (W3) =====
  gemm64x2(OFF_VW2T, OFF_HW3, accV, accH);
  float pgvx = 0.f, plv0 = 0.f, plv1 = 0.f, pH = 0.f;
#pragma unroll
  for (int ht = 0; ht < 4; ++ht) {
    int hb = ht * 16 + q * 4;
    f32x4 g0 = *(const f32x4*)&sC[C_WGV0 + hb];
    f32x4 g1 = *(const f32x4*)&sC[C_WGV1 + hb];
    f32x4 bH = *(const f32x4*)&sC[C_HB3 + hb];
    f32x4 w4 = *(const f32x4*)&sC[C_W4 + hb];
#pragma unroll
    for (int r = 0; r < 4; ++r) {
      float wt = accV[ht][r] * d1V[ht][r];
      pgvx += wt * z1V[ht][r];
      plv0 += wt * g0[r]; plv1 += wt * g1[r];
      float t = tanh_fast(accH[ht][r] + bH[r]);
      pH += t * w4[r];
      tvH[ht][r] = w4[r] * (1.f - t * t);      // v4
    }
  }
  wst(tvH, bufH);

  // ===== S4: H bwd (W3^T) =====
  gemm64(OFF_HW3T, bufH, accH);                // v3
#pragma unroll
  for (int ht = 0; ht < 4; ++ht)
#pragma unroll
    for (int r = 0; r < 4; ++r) tvH[ht][r] = accH[ht][r] * d2H[ht][r];   // bb
  wst(tvH, bufH);

  // ===== S5: H bwd (W2^T) =====
  gemm64(OFF_HW2T, bufH, accH);                // v2
  float pghx = 0.f, plh0 = 0.f, plh1 = 0.f;
#pragma unroll
  for (int ht = 0; ht < 4; ++ht) {
    int hb = ht * 16 + q * 4;
    f32x4 g0 = *(const f32x4*)&sC[C_WGH0 + hb];
    f32x4 g1 = *(const f32x4*)&sC[C_WGH1 + hb];
#pragma unroll
    for (int r = 0; r < 4; ++r) {
      float wt = accH[ht][r] * d1H[ht][r];
      pghx += wt * z1H[ht][r];
      plh0 += wt * g0[r]; plh1 += wt * g1[r];
    }
  }

  // ---- per-element scalars: reduce over q, hand off via LDS transpose ----
  {
    float a0 = redq(plh0), a1 = redq(plh1), a2 = redq(plv0), a3 = redq(plv1);
    float a4 = redq(pghx), a5 = redq(pgvx), a6 = redq(pV), a7 = redq(pH);
    if (q == 0) {
      int col = w * 16 + n;
      sQPs[0][col] = a0; sQPs[1][col] = a1; sQPs[2][col] = a2; sQPs[3][col] = a3;
      sQPs[4][col] = a4; sQPs[5][col] = a5; sQPs[6][col] = a6; sQPs[7][col] = a7;
      sQPs[8][col] = un0; sQPs[9][col] = un1;
    }
  }
  __syncthreads();   // scalars ready
  if (w != 0 && w != 2) return;

  // ====== QP tail: waves 0,2 (SIMD0/SIMD2), 64 full lanes = 64 elems ======
  const int col = (w >> 1) * 64 + lane;
  const int e = blockIdx.x * 128 + col;
  float gh0 = sQPs[0][col], gh1 = sQPs[1][col];
  float gv0 = sQPs[2][col], gv1 = sQPs[3][col];
  float ghx = sQPs[4][col], gvx = sQPs[5][col];
  float V   = 0.5f * sQPs[6][col];
  float H   = sQPs[7][col] + sC[C_HB4];
  un0 = sQPs[8][col]; un1 = sQPs[9][col];
  out[98304 + e]  = V;
  out[163840 + e] = H;

  const float im = 1.0f / 1.2f;
  const float sg = 1e-6f;
  const float d  = 2.f + sg;
  const float rd = 1.f / d;
  const float al = 1.f + im * im;
  const float be = al * (1.f - rd);
  float S00 = be * (gh0 * gh0 + gv0 * gv0) + d;
  float S11 = be * (gh1 * gh1 + gv1 * gv1) + d;
  float S01 = be * (gh0 * gh1 + gv0 * gv1);
  float idet = 1.f / (S00 * S11 - S01 * S01);

  // packed coefficient pairs
  f32x2 IM2; IM2[0] = 1.f; IM2[1] = im;
  f32x2 ghP; ghP[0] = gh0; ghP[1] = gh1;
  f32x2 gvP; gvP[0] = gv0; gvP[1] = gv1;
  f32x2 gHV0; gHV0[0] = gh0; gHV0[1] = gv0;
  f32x2 gHV1; gHV1[0] = gh1; gHV1[1] = gv1;
  f32x2 iA; iA[0] = S11 * idet;  iA[1] = -S01 * idet;   // (i00, i01)
  f32x2 iB; iB[0] = -S01 * idet; iB[1] = S00 * idet;    // (i01, i11)
  f32x2 nqP; nqP[0] = 2.f * un0; nqP[1] = 2.f * un1;    // -q
  f32x2 loA; loA[0] = ghx - H;      loA[1] = ghx * im - H;   // (lo0, lo2)
  f32x2 hiB; hiB[0] = gvx - V;      hiB[1] = gvx * im - V;   // (hi1, hi3)

  // state pairs: A=(Z0,Z2) B=(Z1,Z3) C=(Z4,Z5) D=(Z6,Z7)
  f32x2 ZA = {0.f, 0.f}, ZB = {0.f, 0.f}, ZC = {0.f, 0.f}, ZD = {0.f, 0.f};
  f32x2 YA = {0.f, 0.f}, YB = {0.f, 0.f}, YC = {0.f, 0.f}, YD = {0.f, 0.f};
  f32x2 X01 = {0.f, 0.f}, XP = {0.f, 0.f}, XS = {0.f, 0.f};

  // sg*X proximal terms dropped from rhs: shifts the fixed point by O(1e-6).
#pragma unroll 1
  for (int it = 0; it < 80; ++it) {
    f32x2 tA = ZA - YA, tB = ZB - YB, tC = ZC - YC, tD = ZD - YD;
    float tauh = tA[0] + im * tA[1];
    float tauv = tB[0] + im * tB[1];
    f32x2 bU = nqP + ghP * tauh + gvP * tauv;          // (b0,b1)
    f32x2 bP = tC - tB - 100.f;                        // (b2,b3)
    f32x2 bS = tA + tD - 50.f;                         // (b4,b5)
    float pp = bP[0] + im * bP[1];
    float s2 = bS[0] + im * bS[1];
    f32x2 cb = ghP * s2 - gvP * pp;                    // (cb0,cb1)
    f32x2 ub = bU - cb * rd;                           // (u0b,u1b)
    X01 = iA * ub[0] + iB * ub[1];                     // (X0,X1)
    f32x2 gd = gHV0 * X01[0] + gHV1 * X01[1];          // (gdH,gdV)
    XP = (bP + IM2 * gd[1]) * rd;                      // (X2,X3)
    XS = (bS - IM2 * gd[0]) * rd;                      // (X4,X5)
    f32x2 ztA = IM2 * gd[0] + XS;                      // (zt0,zt2)
    f32x2 ztB = IM2 * gd[1] - XP;                      // (zt1,zt3)

    f32x2 vv, zn;
    vv = ztA + YA; zn[0] = fmaxf(vv[0], loA[0]); zn[1] = fmaxf(vv[1], loA[1]);
    YA = vv - zn; ZA = zn;
    vv = ztB + YB; zn[0] = fminf(vv[0], hiB[0]); zn[1] = fminf(vv[1], hiB[1]);
    YB = vv - zn; ZB = zn;
    vv = XP + YC;  zn[0] = fmaxf(vv[0], 0.f);   zn[1] = fmaxf(vv[1], 0.f);
    YC = vv - zn; ZC = zn;
    vv = XS + YD;  zn[0] = fmaxf(vv[0], 0.f);   zn[1] = fmaxf(vv[1], 0.f);
    YD = vv - zn; ZD = zn;
  }

  float relax = 0.5f * (XP[0] + XP[1]);
  const float cc = 0.5f * (1.f + im);
  float Vdot = cc * (gv0 * X01[0] + gv1 * X01[1] - gvx);
  float Hdot = cc * (gh0 * X01[0] + gh1 * X01[1] - ghx);

  f32x2 uo; uo[0] = X01[0]; uo[1] = X01[1];
  *(f32x2*)&out[2 * e] = uo;
  out[65536 + e]  = relax;
  out[131072 + e] = Vdot;
  out[196608 + e] = Hdot;
}

extern "C" void kernel_launch(void* const* d_in, const int* in_sizes, int n_in,
                              void* d_out, int out_size, void* d_ws, size_t ws_size,
                              hipStream_t stream) {
  (void)in_sizes; (void)n_in; (void)out_size; (void)d_ws; (void)ws_size;
  fused_kernel<<<256, 512, 0, stream>>>(
      d_in[0], d_in[1], d_in[2], d_in[3], d_in[4], d_in[5], d_in[6],
      d_in[7], d_in[8], d_in[9], d_in[10], d_in[11], d_in[12],
      d_in[13], d_in[14], (float*)d_out);
}